// Round 6
// baseline (1147.775 us; speedup 1.0000x reference)
//
#include <hip/hip_runtime.h>

#define H   128
#define NU  200000
#define NM  50000
#define NE  600000

typedef __attribute__((ext_vector_type(8))) short bf16x8;
typedef __attribute__((ext_vector_type(4))) float f32x4;
typedef unsigned short ushort_t;
typedef unsigned int uint_t;

__device__ __forceinline__ ushort_t f2bf(float x) {
    uint_t b = __float_as_uint(x);
    return (ushort_t)((b + 0x7FFF + ((b >> 16) & 1)) >> 16);  // RNE
}

// ---------------- encoders: h = bf16(relu(x @ W + b)), K small ----------------
__global__ void __launch_bounds__(256)
encode_bf16_kernel(const float* __restrict__ x, const float* __restrict__ W,
                   const float* __restrict__ b, ushort_t* __restrict__ h,
                   int n, int K) {
    int idx = blockIdx.x * 256 + threadIdx.x;
    if (idx >= n * 16) return;
    int r = idx >> 4, c0 = (idx & 15) * 8;
    float4 ba = *(const float4*)&b[c0], bb = *(const float4*)&b[c0 + 4];
    float acc[8] = {ba.x, ba.y, ba.z, ba.w, bb.x, bb.y, bb.z, bb.w};
    for (int k = 0; k < K; k++) {
        float xv = x[r * K + k];
        float4 wa = *(const float4*)&W[k * H + c0], wb = *(const float4*)&W[k * H + c0 + 4];
        acc[0] = fmaf(xv, wa.x, acc[0]); acc[1] = fmaf(xv, wa.y, acc[1]);
        acc[2] = fmaf(xv, wa.z, acc[2]); acc[3] = fmaf(xv, wa.w, acc[3]);
        acc[4] = fmaf(xv, wb.x, acc[4]); acc[5] = fmaf(xv, wb.y, acc[5]);
        acc[6] = fmaf(xv, wb.z, acc[6]); acc[7] = fmaf(xv, wb.w, acc[7]);
    }
    union { ushort_t u[8]; uint4 q; } pk;
#pragma unroll
    for (int j = 0; j < 8; j++) pk.u[j] = f2bf(fmaxf(acc[j], 0.f));
    *(uint4*)&h[(size_t)r * H + c0] = pk.q;
}

// ---------------- CSR build ----------------
__global__ void count_kernel(const int* __restrict__ ei, int* cu, int* cm, int n) {
    int e = blockIdx.x * blockDim.x + threadIdx.x;
    if (e >= n) return;
    atomicAdd(&cu[ei[e]], 1);
    atomicAdd(&cm[ei[NE + e]], 1);
}

// ---------- 3-phase multi-block exclusive scan (2048 elements / block) ----------
__global__ void __launch_bounds__(256)
scanA_kernel(const int* __restrict__ cnt, int* __restrict__ bsum, int n) {
    __shared__ int s[256];
    int b = blockIdx.x, t = threadIdx.x;
    int base = b * 2048 + t * 8;
    int sum = 0;
    if (base + 8 <= n) {
        int4 a = *(const int4*)&cnt[base];
        int4 c = *(const int4*)&cnt[base + 4];
        sum = a.x + a.y + a.z + a.w + c.x + c.y + c.z + c.w;
    } else {
        for (int j = 0; j < 8; j++) { int i = base + j; if (i < n) sum += cnt[i]; }
    }
    s[t] = sum;
    __syncthreads();
    for (int off = 128; off >= 1; off >>= 1) {
        if (t < off) s[t] += s[t + off];
        __syncthreads();
    }
    if (t == 0) bsum[b] = s[0];
}

__global__ void __launch_bounds__(256)
scanB_kernel(const int* __restrict__ bsum, int* __restrict__ boff, int nb,
             int* __restrict__ rp_total) {
    __shared__ int s[256];
    int t = threadIdx.x;
    int v = (t < nb) ? bsum[t] : 0;
    s[t] = v;
    __syncthreads();
    for (int off = 1; off < 256; off <<= 1) {
        int x = (t >= off) ? s[t - off] : 0;
        __syncthreads();
        s[t] += x;
        __syncthreads();
    }
    if (t < nb) boff[t] = s[t] - v;
    if (t == 255) rp_total[0] = s[255];
}

__global__ void __launch_bounds__(256)
scanC_kernel(const int* __restrict__ cnt, const int* __restrict__ boff,
             int* __restrict__ rp, int n) {
    __shared__ int s[256];
    int b = blockIdx.x, t = threadIdx.x;
    int base = b * 2048 + t * 8;
    int v[8];
    int sum = 0;
    if (base + 8 <= n) {
        int4 a = *(const int4*)&cnt[base];
        int4 c = *(const int4*)&cnt[base + 4];
        v[0] = a.x; v[1] = a.y; v[2] = a.z; v[3] = a.w;
        v[4] = c.x; v[5] = c.y; v[6] = c.z; v[7] = c.w;
#pragma unroll
        for (int j = 0; j < 8; j++) sum += v[j];
    } else {
#pragma unroll
        for (int j = 0; j < 8; j++) { int i = base + j; v[j] = (i < n) ? cnt[i] : 0; sum += v[j]; }
    }
    s[t] = sum;
    __syncthreads();
    for (int off = 1; off < 256; off <<= 1) {
        int x = (t >= off) ? s[t - off] : 0;
        __syncthreads();
        s[t] += x;
        __syncthreads();
    }
    int run = boff[b] + s[t] - sum;
    if (base + 8 <= n) {
        int o[8];
#pragma unroll
        for (int j = 0; j < 8; j++) { o[j] = run; run += v[j]; }
        *(int4*)&rp[base]     = make_int4(o[0], o[1], o[2], o[3]);
        *(int4*)&rp[base + 4] = make_int4(o[4], o[5], o[6], o[7]);
    } else {
#pragma unroll
        for (int j = 0; j < 8; j++) { int i = base + j; if (i < n) rp[i] = run; run += v[j]; }
    }
}

__global__ void fill_kernel(const int* __restrict__ ei, const int* __restrict__ rpu,
                            const int* __restrict__ rpm, int* cu, int* cm,
                            int* __restrict__ eu, int* __restrict__ em, int n) {
    int e = blockIdx.x * blockDim.x + threadIdx.x;
    if (e >= n) return;
    int s = ei[e], d = ei[NE + e];
    eu[rpu[s] + atomicAdd(&cu[s], 1)] = d;
    em[rpm[d] + atomicAdd(&cm[d], 1)] = s;
}

// ---------------- weight converters ----------------
__global__ void convert_w_kernel(const float* __restrict__ c1w, ushort_t* __restrict__ outT) {
    int i = blockIdx.x * 256 + threadIdx.x;
    if (i >= 384 * 128) return;
    int k = i >> 7, n = i & 127;
    outT[n * 384 + k] = f2bf(c1w[i]);
}

__global__ void convert_conv_w_kernel(const float* __restrict__ wl, const float* __restrict__ wr,
                                      ushort_t* __restrict__ outT) {
    int i = blockIdx.x * 256 + threadIdx.x;
    if (i >= 128 * 256) return;
    int col = i >> 8, k = i & 255;
    float v = (k < 128) ? wl[k * H + col] : wr[(k - 128) * H + col];
    outT[i] = f2bf(v);
}

// ---------------- fused SAGE conv: gather+mean+MFMA in one kernel ----------------
// out = bf16(relu([mean_nb | self] @ wT' + bl)), 64 nodes/block, 256 threads (4 waves).
// Wave w gathers+means neighbors for rows w*16..w*16+15 straight into the LDS A-tile.
__global__ void __launch_bounds__(256)
conv_fused_kernel(const ushort_t* __restrict__ h_nb, const ushort_t* __restrict__ self,
                  const int* __restrict__ rp, const int* __restrict__ nbl,
                  const ushort_t* __restrict__ wT, const float* __restrict__ bl,
                  ushort_t* __restrict__ out, int n) {
    const int NT = 64;
    int node0 = blockIdx.x * NT;
    int t = threadIdx.x, lane = t & 63, w = t >> 6;
    int l15 = lane & 15, koff = lane >> 4;
    __shared__ ushort_t As[NT * 256];   // 32 KB

    bf16x8 bw[8][2];
#pragma unroll
    for (int ks = 0; ks < 8; ks++)
#pragma unroll
        for (int n1 = 0; n1 < 2; n1++) {
            int col = w * 32 + n1 * 16 + l15;
            bw[ks][n1] = *reinterpret_cast<const bf16x8*>(&wT[col * 256 + ks * 32 + koff * 8]);
        }

    char* Ab = (char*)As;
    // self rows -> granules 16..31
#pragma unroll
    for (int it = 0; it < 4; it++) {
        int lin = it * 256 + t;
        int row = lin >> 4, g = (lin & 15) + 16;
        int node = node0 + row; if (node >= n) node = n - 1;
        *(uint4*)(Ab + row * 512 + ((g ^ (row & 7)) << 4)) =
            *(const uint4*)&self[(size_t)node * H + (g - 16) * 8];
    }
    // gather + mean -> granules 0..15 (lane covers cols lane*2, lane*2+1)
    for (int i = 0; i < 16; i++) {
        int row = w * 16 + i;
        int node = node0 + row;
        float a0 = 0.f, a1 = 0.f;
        int beg = 0, end = 0;
        if (node < n) { beg = rp[node]; end = rp[node + 1]; }
        int j = beg;
        for (; j + 1 < end; j += 2) {
            uint_t v0 = *(const uint_t*)&h_nb[(size_t)nbl[j] * H + lane * 2];
            uint_t v1 = *(const uint_t*)&h_nb[(size_t)nbl[j + 1] * H + lane * 2];
            a0 += __uint_as_float((v0 & 0xffffu) << 16);
            a1 += __uint_as_float(v0 & 0xffff0000u);
            a0 += __uint_as_float((v1 & 0xffffu) << 16);
            a1 += __uint_as_float(v1 & 0xffff0000u);
        }
        if (j < end) {
            uint_t v0 = *(const uint_t*)&h_nb[(size_t)nbl[j] * H + lane * 2];
            a0 += __uint_as_float((v0 & 0xffffu) << 16);
            a1 += __uint_as_float(v0 & 0xffff0000u);
        }
        int deg = end - beg;
        float inv = 1.0f / (float)(deg > 1 ? deg : 1);
        uint_t r = (uint_t)f2bf(a0 * inv) | ((uint_t)f2bf(a1 * inv) << 16);
        *(uint_t*)(Ab + row * 512 + (((lane >> 2) ^ (row & 7)) << 4) + (lane & 3) * 4) = r;
    }
    __syncthreads();

    int sw = l15 & 7;
    float bias0 = bl[w * 32 + l15];
    float bias1 = bl[w * 32 + 16 + l15];
    f32x4 acc[4][2];
#pragma unroll
    for (int rg = 0; rg < 4; rg++) {
        acc[rg][0] = (f32x4){bias0, bias0, bias0, bias0};
        acc[rg][1] = (f32x4){bias1, bias1, bias1, bias1};
    }
#pragma unroll
    for (int ks = 0; ks < 8; ks++) {
#pragma unroll
        for (int rg = 0; rg < 4; rg++) {
            int row = rg * 16 + l15;
            const bf16x8 a = *reinterpret_cast<const bf16x8*>(
                Ab + row * 512 + (((ks * 4 + koff) ^ sw) << 4));
            acc[rg][0] = __builtin_amdgcn_mfma_f32_16x16x32_bf16(a, bw[ks][0], acc[rg][0], 0, 0, 0);
            acc[rg][1] = __builtin_amdgcn_mfma_f32_16x16x32_bf16(a, bw[ks][1], acc[rg][1], 0, 0, 0);
        }
    }

#pragma unroll
    for (int rg = 0; rg < 4; rg++)
#pragma unroll
        for (int reg = 0; reg < 4; reg++) {
            int node = node0 + rg * 16 + koff * 4 + reg;
            if (node < n) {
                out[(size_t)node * H + w * 32 + l15]      = f2bf(fmaxf(acc[rg][0][reg], 0.f));
                out[(size_t)node * H + w * 32 + 16 + l15] = f2bf(fmaxf(acc[rg][1][reg], 0.f));
            }
        }
}

// ---------------- edge MLP via MFMA (ET=32 for occupancy) ----------------
__global__ void __launch_bounds__(256)
edge_mlp_mfma_kernel(const ushort_t* __restrict__ h_u, const ushort_t* __restrict__ h_m,
                     const float* __restrict__ ea, const float* __restrict__ ew,
                     const float* __restrict__ ebias,
                     const ushort_t* __restrict__ c1wT, const float* __restrict__ c1b,
                     const float* __restrict__ c2w, const float* __restrict__ c2b,
                     const int* __restrict__ ei, float* __restrict__ out) {
    const int ET = 32;
    int e0 = blockIdx.x * ET;
    int t = threadIdx.x;
    int lane = t & 63, w = t >> 6;
    int l15 = lane & 15, koff = lane >> 4;

    __shared__ ushort_t As[ET * 384];   // 24 KB, XOR-swizzled 16B granules
    __shared__ float part[4 * ET];
    __shared__ int se[ET], de[ET];

    if (t < ET) {
        se[t] = ei[e0 + t];
        de[t] = ei[NE + e0 + t];
    }

    bf16x8 bf_[12][2];
#pragma unroll
    for (int ks = 0; ks < 12; ks++)
#pragma unroll
        for (int n1 = 0; n1 < 2; n1++) {
            int col = w * 32 + n1 * 16 + l15;
            bf_[ks][n1] = *reinterpret_cast<const bf16x8*>(&c1wT[col * 384 + ks * 32 + koff * 8]);
        }

    __syncthreads();

    char* Ab = (char*)As;
#pragma unroll
    for (int it = 0; it < 6; it++) {
        int lin = it * 256 + t;          // 0..1535 = 32 rows x 48 granules
        int row = lin / 48;
        int g = lin - row * 48;
        if (g < 32) {
            const ushort_t* s = (g < 16) ? &h_u[(size_t)se[row] * H + g * 8]
                                         : &h_m[(size_t)de[row] * H + (g - 16) * 8];
            *(uint4*)(Ab + row * 768 + ((g ^ (row & 7)) << 4)) = *(const uint4*)s;
        } else {
            int c = (g - 32) * 8;
            float a0 = ea[(size_t)(e0 + row) * 2], a1 = ea[(size_t)(e0 + row) * 2 + 1];
            float4 w0a = *(const float4*)&ew[c];
            float4 w0b = *(const float4*)&ew[c + 4];
            float4 w1a = *(const float4*)&ew[H + c];
            float4 w1b = *(const float4*)&ew[H + c + 4];
            float4 bba = *(const float4*)&ebias[c];
            float4 bbb = *(const float4*)&ebias[c + 4];
            float v[8];
            v[0] = fmaxf(fmaf(a0, w0a.x, fmaf(a1, w1a.x, bba.x)), 0.f);
            v[1] = fmaxf(fmaf(a0, w0a.y, fmaf(a1, w1a.y, bba.y)), 0.f);
            v[2] = fmaxf(fmaf(a0, w0a.z, fmaf(a1, w1a.z, bba.z)), 0.f);
            v[3] = fmaxf(fmaf(a0, w0a.w, fmaf(a1, w1a.w, bba.w)), 0.f);
            v[4] = fmaxf(fmaf(a0, w0b.x, fmaf(a1, w1b.x, bbb.x)), 0.f);
            v[5] = fmaxf(fmaf(a0, w0b.y, fmaf(a1, w1b.y, bbb.y)), 0.f);
            v[6] = fmaxf(fmaf(a0, w0b.z, fmaf(a1, w1b.z, bbb.z)), 0.f);
            v[7] = fmaxf(fmaf(a0, w0b.w, fmaf(a1, w1b.w, bbb.w)), 0.f);
            union { ushort_t u[8]; uint4 q; } pk;
#pragma unroll
            for (int j = 0; j < 8; j++) pk.u[j] = f2bf(v[j]);
            *(uint4*)(Ab + row * 768 + ((g ^ (row & 7)) << 4)) = pk.q;
        }
    }
    __syncthreads();

    int sw = l15 & 7;
    float bias0 = c1b[w * 32 + l15];
    float bias1 = c1b[w * 32 + 16 + l15];
    f32x4 acc[2][2];
#pragma unroll
    for (int rg = 0; rg < 2; rg++) {
        acc[rg][0] = (f32x4){bias0, bias0, bias0, bias0};
        acc[rg][1] = (f32x4){bias1, bias1, bias1, bias1};
    }
#pragma unroll
    for (int ks = 0; ks < 12; ks++) {
#pragma unroll
        for (int rg = 0; rg < 2; rg++) {
            int row = rg * 16 + l15;
            const bf16x8 a = *reinterpret_cast<const bf16x8*>(
                Ab + row * 768 + (((ks * 4 + koff) ^ sw) << 4));
            acc[rg][0] = __builtin_amdgcn_mfma_f32_16x16x32_bf16(a, bf_[ks][0], acc[rg][0], 0, 0, 0);
            acc[rg][1] = __builtin_amdgcn_mfma_f32_16x16x32_bf16(a, bf_[ks][1], acc[rg][1], 0, 0, 0);
        }
    }

    float c2v0 = c2w[w * 32 + l15];
    float c2v1 = c2w[w * 32 + 16 + l15];
#pragma unroll
    for (int rg = 0; rg < 2; rg++) {
#pragma unroll
        for (int reg = 0; reg < 4; reg++) {
            float p = fmaxf(acc[rg][0][reg], 0.f) * c2v0 + fmaxf(acc[rg][1][reg], 0.f) * c2v1;
#pragma unroll
            for (int off = 8; off >= 1; off >>= 1) p += __shfl_xor(p, off, 64);
            if (l15 == 0) part[w * ET + rg * 16 + koff * 4 + reg] = p;
        }
    }
    __syncthreads();
    if (t < ET) {
        out[e0 + t] = part[t] + part[ET + t] + part[2 * ET + t] + part[3 * ET + t] + c2b[0];
    }
}

extern "C" void kernel_launch(void* const* d_in, const int* in_sizes, int n_in,
                              void* d_out, int out_size, void* d_ws, size_t ws_size,
                              hipStream_t stream) {
    const float* user_x     = (const float*)d_in[0];
    const float* merchant_x = (const float*)d_in[1];
    const float* edge_attr  = (const float*)d_in[2];
    const float* user_w     = (const float*)d_in[3];
    const float* user_b     = (const float*)d_in[4];
    const float* merch_w    = (const float*)d_in[5];
    const float* merch_b    = (const float*)d_in[6];
    const float* edge_w     = (const float*)d_in[7];
    const float* edge_b     = (const float*)d_in[8];
    const float* u2m_wl     = (const float*)d_in[9];
    const float* u2m_bl     = (const float*)d_in[10];
    const float* u2m_wr     = (const float*)d_in[11];
    const float* m2u_wl     = (const float*)d_in[12];
    const float* m2u_bl     = (const float*)d_in[13];
    const float* m2u_wr     = (const float*)d_in[14];
    const float* c1w        = (const float*)d_in[15];
    const float* c1b        = (const float*)d_in[16];
    const float* c2w        = (const float*)d_in[17];
    const float* c2b        = (const float*)d_in[18];
    const int*   ei         = (const int*)d_in[19];
    float* out = (float*)d_out;

    ushort_t* hu   = (ushort_t*)d_ws;
    ushort_t* hm   = hu  + (size_t)NU * H;
    ushort_t* hu2  = hm  + (size_t)NM * H;
    ushort_t* hm2  = hu2 + (size_t)NU * H;
    ushort_t* c1wT = hm2 + (size_t)NM * H;
    ushort_t* wTc  = c1wT + 384 * 128;
    int* rpu = (int*)(wTc + 4 * 128 * 256);
    int* rpm = rpu + (NU + 1);
    int* cu  = rpm + (NM + 1);
    int* cm  = cu + NU;
    int* eu  = cm + NM;
    int* em  = eu + NE;
    int* bsum_u = em + NE;
    int* boff_u = bsum_u + 128;
    int* bsum_m = boff_u + 128;
    int* boff_m = bsum_m + 128;

    const int NBU = (NU + 2047) / 2048;
    const int NBM = (NM + 2047) / 2048;

    hipMemsetAsync(cu, 0, (size_t)(NU + NM) * sizeof(int), stream);

    encode_bf16_kernel<<<(NU * 16 + 255) / 256, 256, 0, stream>>>(user_x, user_w, user_b, hu, NU, 3);
    encode_bf16_kernel<<<(NM * 16 + 255) / 256, 256, 0, stream>>>(merchant_x, merch_w, merch_b, hm, NM, 2);
    convert_w_kernel<<<(384 * 128 + 255) / 256, 256, 0, stream>>>(c1w, c1wT);
    for (int l = 0; l < 2; l++) {
        convert_conv_w_kernel<<<128, 256, 0, stream>>>(
            u2m_wl + (size_t)l * H * H, u2m_wr + (size_t)l * H * H, wTc + (size_t)l * 128 * 256);
        convert_conv_w_kernel<<<128, 256, 0, stream>>>(
            m2u_wl + (size_t)l * H * H, m2u_wr + (size_t)l * H * H, wTc + (size_t)(2 + l) * 128 * 256);
    }

    count_kernel<<<(NE + 255) / 256, 256, 0, stream>>>(ei, cu, cm, NE);
    scanA_kernel<<<NBU, 256, 0, stream>>>(cu, bsum_u, NU);
    scanB_kernel<<<1, 256, 0, stream>>>(bsum_u, boff_u, NBU, rpu + NU);
    scanC_kernel<<<NBU, 256, 0, stream>>>(cu, boff_u, rpu, NU);
    scanA_kernel<<<NBM, 256, 0, stream>>>(cm, bsum_m, NM);
    scanB_kernel<<<1, 256, 0, stream>>>(bsum_m, boff_m, NBM, rpm + NM);
    scanC_kernel<<<NBM, 256, 0, stream>>>(cm, boff_m, rpm, NM);
    hipMemsetAsync(cu, 0, (size_t)(NU + NM) * sizeof(int), stream);
    fill_kernel<<<(NE + 255) / 256, 256, 0, stream>>>(ei, rpu, rpm, cu, cm, eu, em, NE);

    const ushort_t* pu = hu; const ushort_t* pm = hm;
    ushort_t* qu = hu2; ushort_t* qm = hm2;
    for (int l = 0; l < 2; l++) {
        conv_fused_kernel<<<(NM + 63) / 64, 256, 0, stream>>>(
            pu, pm, rpm, em, wTc + (size_t)l * 128 * 256, u2m_bl + (size_t)l * H, qm, NM);
        conv_fused_kernel<<<(NU + 63) / 64, 256, 0, stream>>>(
            pm, pu, rpu, eu, wTc + (size_t)(2 + l) * 128 * 256, m2u_bl + (size_t)l * H, qu, NU);
        const ushort_t* tu = pu; pu = qu; qu = (ushort_t*)tu;
        const ushort_t* tm = pm; pm = qm; qm = (ushort_t*)tm;
    }

    edge_mlp_mfma_kernel<<<NE / 32, 256, 0, stream>>>(pu, pm, edge_attr, edge_w, edge_b,
                                                      c1wT, c1b, c2w, c2b, ei, out);
}

// Round 7
// 1059.825 us; speedup vs baseline: 1.0830x; 1.0830x over previous
//
#include <hip/hip_runtime.h>

#define H   128
#define NU  200000
#define NM  50000
#define NE  600000

typedef __attribute__((ext_vector_type(8))) short bf16x8;
typedef __attribute__((ext_vector_type(4))) float f32x4;
typedef unsigned short ushort_t;
typedef unsigned int uint_t;

__device__ __forceinline__ ushort_t f2bf(float x) {
    uint_t b = __float_as_uint(x);
    return (ushort_t)((b + 0x7FFF + ((b >> 16) & 1)) >> 16);  // RNE
}

// ---------------- encoders: h = bf16(relu(x @ W + b)), K small ----------------
__global__ void __launch_bounds__(256)
encode_bf16_kernel(const float* __restrict__ x, const float* __restrict__ W,
                   const float* __restrict__ b, ushort_t* __restrict__ h,
                   int n, int K) {
    int idx = blockIdx.x * 256 + threadIdx.x;
    if (idx >= n * 16) return;
    int r = idx >> 4, c0 = (idx & 15) * 8;
    float4 ba = *(const float4*)&b[c0], bb = *(const float4*)&b[c0 + 4];
    float acc[8] = {ba.x, ba.y, ba.z, ba.w, bb.x, bb.y, bb.z, bb.w};
    for (int k = 0; k < K; k++) {
        float xv = x[r * K + k];
        float4 wa = *(const float4*)&W[k * H + c0], wb = *(const float4*)&W[k * H + c0 + 4];
        acc[0] = fmaf(xv, wa.x, acc[0]); acc[1] = fmaf(xv, wa.y, acc[1]);
        acc[2] = fmaf(xv, wa.z, acc[2]); acc[3] = fmaf(xv, wa.w, acc[3]);
        acc[4] = fmaf(xv, wb.x, acc[4]); acc[5] = fmaf(xv, wb.y, acc[5]);
        acc[6] = fmaf(xv, wb.z, acc[6]); acc[7] = fmaf(xv, wb.w, acc[7]);
    }
    union { ushort_t u[8]; uint4 q; } pk;
#pragma unroll
    for (int j = 0; j < 8; j++) pk.u[j] = f2bf(fmaxf(acc[j], 0.f));
    *(uint4*)&h[(size_t)r * H + c0] = pk.q;
}

// ---------------- CSR build ----------------
__global__ void count_kernel(const int* __restrict__ ei, int* cu, int* cm, int n) {
    int e = blockIdx.x * blockDim.x + threadIdx.x;
    if (e >= n) return;
    atomicAdd(&cu[ei[e]], 1);
    atomicAdd(&cm[ei[NE + e]], 1);
}

// ---------- 3-phase multi-block exclusive scan (2048 elements / block) ----------
__global__ void __launch_bounds__(256)
scanA_kernel(const int* __restrict__ cnt, int* __restrict__ bsum, int n) {
    __shared__ int s[256];
    int b = blockIdx.x, t = threadIdx.x;
    int base = b * 2048 + t * 8;
    int sum = 0;
    if (base + 8 <= n) {
        int4 a = *(const int4*)&cnt[base];
        int4 c = *(const int4*)&cnt[base + 4];
        sum = a.x + a.y + a.z + a.w + c.x + c.y + c.z + c.w;
    } else {
        for (int j = 0; j < 8; j++) { int i = base + j; if (i < n) sum += cnt[i]; }
    }
    s[t] = sum;
    __syncthreads();
    for (int off = 128; off >= 1; off >>= 1) {
        if (t < off) s[t] += s[t + off];
        __syncthreads();
    }
    if (t == 0) bsum[b] = s[0];
}

__global__ void __launch_bounds__(256)
scanB_kernel(const int* __restrict__ bsum, int* __restrict__ boff, int nb,
             int* __restrict__ rp_total) {
    __shared__ int s[256];
    int t = threadIdx.x;
    int v = (t < nb) ? bsum[t] : 0;
    s[t] = v;
    __syncthreads();
    for (int off = 1; off < 256; off <<= 1) {
        int x = (t >= off) ? s[t - off] : 0;
        __syncthreads();
        s[t] += x;
        __syncthreads();
    }
    if (t < nb) boff[t] = s[t] - v;
    if (t == 255) rp_total[0] = s[255];
}

__global__ void __launch_bounds__(256)
scanC_kernel(const int* __restrict__ cnt, const int* __restrict__ boff,
             int* __restrict__ rp, int n) {
    __shared__ int s[256];
    int b = blockIdx.x, t = threadIdx.x;
    int base = b * 2048 + t * 8;
    int v[8];
    int sum = 0;
    if (base + 8 <= n) {
        int4 a = *(const int4*)&cnt[base];
        int4 c = *(const int4*)&cnt[base + 4];
        v[0] = a.x; v[1] = a.y; v[2] = a.z; v[3] = a.w;
        v[4] = c.x; v[5] = c.y; v[6] = c.z; v[7] = c.w;
#pragma unroll
        for (int j = 0; j < 8; j++) sum += v[j];
    } else {
#pragma unroll
        for (int j = 0; j < 8; j++) { int i = base + j; v[j] = (i < n) ? cnt[i] : 0; sum += v[j]; }
    }
    s[t] = sum;
    __syncthreads();
    for (int off = 1; off < 256; off <<= 1) {
        int x = (t >= off) ? s[t - off] : 0;
        __syncthreads();
        s[t] += x;
        __syncthreads();
    }
    int run = boff[b] + s[t] - sum;
    if (base + 8 <= n) {
        int o[8];
#pragma unroll
        for (int j = 0; j < 8; j++) { o[j] = run; run += v[j]; }
        *(int4*)&rp[base]     = make_int4(o[0], o[1], o[2], o[3]);
        *(int4*)&rp[base + 4] = make_int4(o[4], o[5], o[6], o[7]);
    } else {
#pragma unroll
        for (int j = 0; j < 8; j++) { int i = base + j; if (i < n) rp[i] = run; run += v[j]; }
    }
}

__global__ void fill_kernel(const int* __restrict__ ei, const int* __restrict__ rpu,
                            const int* __restrict__ rpm, int* cu, int* cm,
                            int* __restrict__ eu, int* __restrict__ em, int n) {
    int e = blockIdx.x * blockDim.x + threadIdx.x;
    if (e >= n) return;
    int s = ei[e], d = ei[NE + e];
    eu[rpu[s] + atomicAdd(&cu[s], 1)] = d;
    em[rpm[d] + atomicAdd(&cm[d], 1)] = s;
}

// ---------------- segment mean over bf16 rows (fp32 accum), 1 wave per node ----------------
__global__ void __launch_bounds__(256)
agg_bf16_kernel(const ushort_t* __restrict__ h_nb, const int* __restrict__ rp,
                const int* __restrict__ nbl, ushort_t* __restrict__ agg, int n) {
    int node = blockIdx.x * 4 + (threadIdx.x >> 6);
    if (node >= n) return;
    int lane = threadIdx.x & 63;
    int beg = rp[node], end = rp[node + 1];
    float a0 = 0.f, a1 = 0.f;
    for (int j = beg; j < end; j++) {
        uint_t v = *(const uint_t*)&h_nb[(size_t)nbl[j] * H + lane * 2];
        a0 += __uint_as_float((v & 0xffffu) << 16);
        a1 += __uint_as_float(v & 0xffff0000u);
    }
    int deg = end - beg;
    float inv = 1.0f / (float)(deg > 1 ? deg : 1);
    uint_t r = (uint_t)f2bf(a0 * inv) | ((uint_t)f2bf(a1 * inv) << 16);
    *(uint_t*)&agg[(size_t)node * H + lane * 2] = r;
}

// ---------------- weight converters ----------------
__global__ void convert_w_kernel(const float* __restrict__ c1w, ushort_t* __restrict__ outT) {
    int i = blockIdx.x * 256 + threadIdx.x;
    if (i >= 384 * 128) return;
    int k = i >> 7, n = i & 127;
    outT[n * 384 + k] = f2bf(c1w[i]);
}

__global__ void convert_conv_w_kernel(const float* __restrict__ wl, const float* __restrict__ wr,
                                      ushort_t* __restrict__ outT) {
    int i = blockIdx.x * 256 + threadIdx.x;
    if (i >= 128 * 256) return;
    int col = i >> 8, k = i & 255;
    float v = (k < 128) ? wl[k * H + col] : wr[(k - 128) * H + col];
    outT[i] = f2bf(v);
}

// ---------------- SAGE conv via MFMA (persistent multi-tile) ----------------
// out = bf16(relu([agg|self] @ wT' + bl)), 64 nodes/tile, 256 threads (4 waves).
// B-slice loaded once per block, grid-stride over node tiles.
__global__ void __launch_bounds__(256)
conv_mfma_kernel(const ushort_t* __restrict__ agg, const ushort_t* __restrict__ self,
                 const ushort_t* __restrict__ wT, const float* __restrict__ bl,
                 ushort_t* __restrict__ out, int n, int ntiles) {
    int t = threadIdx.x, lane = t & 63, w = t >> 6;
    int l15 = lane & 15, koff = lane >> 4;
    __shared__ ushort_t As[64 * 256];   // 32 KB

    bf16x8 bw[8][2];
#pragma unroll
    for (int ks = 0; ks < 8; ks++)
#pragma unroll
        for (int n1 = 0; n1 < 2; n1++) {
            int col = w * 32 + n1 * 16 + l15;
            bw[ks][n1] = *reinterpret_cast<const bf16x8*>(&wT[col * 256 + ks * 32 + koff * 8]);
        }
    float bias0 = bl[w * 32 + l15];
    float bias1 = bl[w * 32 + 16 + l15];
    int sw = l15 & 7;
    char* Ab = (char*)As;

    for (int tile = blockIdx.x; tile < ntiles; tile += gridDim.x) {
        int node0 = tile * 64;
#pragma unroll
        for (int it = 0; it < 8; it++) {
            int lin = it * 256 + t;
            int row = lin >> 5, g = lin & 31;
            int node = node0 + row; if (node >= n) node = n - 1;
            const ushort_t* s = (g < 16) ? &agg[(size_t)node * H + g * 8]
                                         : &self[(size_t)node * H + (g - 16) * 8];
            *(uint4*)(Ab + row * 512 + ((g ^ (row & 7)) << 4)) = *(const uint4*)s;
        }
        __syncthreads();

        f32x4 acc[4][2];
#pragma unroll
        for (int rg = 0; rg < 4; rg++) {
            acc[rg][0] = (f32x4){bias0, bias0, bias0, bias0};
            acc[rg][1] = (f32x4){bias1, bias1, bias1, bias1};
        }
#pragma unroll
        for (int ks = 0; ks < 8; ks++) {
#pragma unroll
            for (int rg = 0; rg < 4; rg++) {
                int row = rg * 16 + l15;
                const bf16x8 a = *reinterpret_cast<const bf16x8*>(
                    Ab + row * 512 + (((ks * 4 + koff) ^ sw) << 4));
                acc[rg][0] = __builtin_amdgcn_mfma_f32_16x16x32_bf16(a, bw[ks][0], acc[rg][0], 0, 0, 0);
                acc[rg][1] = __builtin_amdgcn_mfma_f32_16x16x32_bf16(a, bw[ks][1], acc[rg][1], 0, 0, 0);
            }
        }

#pragma unroll
        for (int rg = 0; rg < 4; rg++)
#pragma unroll
            for (int reg = 0; reg < 4; reg++) {
                int node = node0 + rg * 16 + koff * 4 + reg;
                if (node < n) {
                    out[(size_t)node * H + w * 32 + l15]      = f2bf(fmaxf(acc[rg][0][reg], 0.f));
                    out[(size_t)node * H + w * 32 + 16 + l15] = f2bf(fmaxf(acc[rg][1][reg], 0.f));
                }
            }
        __syncthreads();  // all MFMA reads of As done before next tile's stage
    }
}

// ---------------- edge MLP via MFMA (persistent multi-tile, ET=64) ----------------
__global__ void __launch_bounds__(256)
edge_mlp_mfma_kernel(const ushort_t* __restrict__ h_u, const ushort_t* __restrict__ h_m,
                     const float* __restrict__ ea, const float* __restrict__ ew,
                     const float* __restrict__ ebias,
                     const ushort_t* __restrict__ c1wT, const float* __restrict__ c1b,
                     const float* __restrict__ c2w, const float* __restrict__ c2b,
                     const int* __restrict__ ei, float* __restrict__ out, int ntiles) {
    const int ET = 64;
    int t = threadIdx.x;
    int lane = t & 63, w = t >> 6;
    int l15 = lane & 15, koff = lane >> 4;

    __shared__ ushort_t As[ET * 384];   // 48 KB, XOR-swizzled 16B granules
    __shared__ float part[4 * ET];
    __shared__ int se[ET], de[ET];

    // tile-invariant: B slice, biases, layer-2 weights
    bf16x8 bf_[12][2];
#pragma unroll
    for (int ks = 0; ks < 12; ks++)
#pragma unroll
        for (int n1 = 0; n1 < 2; n1++) {
            int col = w * 32 + n1 * 16 + l15;
            bf_[ks][n1] = *reinterpret_cast<const bf16x8*>(&c1wT[col * 384 + ks * 32 + koff * 8]);
        }
    float bias0 = c1b[w * 32 + l15];
    float bias1 = c1b[w * 32 + 16 + l15];
    float c2v0 = c2w[w * 32 + l15];
    float c2v1 = c2w[w * 32 + 16 + l15];
    float bias2 = c2b[0];
    int sw = l15 & 7;
    char* Ab = (char*)As;

    for (int tile = blockIdx.x; tile < ntiles; tile += gridDim.x) {
        int e0 = tile * ET;
        if (t < ET) {
            se[t] = ei[e0 + t];
            de[t] = ei[NE + e0 + t];
        }
        __syncthreads();

#pragma unroll
        for (int it = 0; it < 12; it++) {
            int lin = it * 256 + t;       // 0..3071 = 64 rows x 48 granules
            int row = lin / 48;
            int g = lin - row * 48;
            if (g < 32) {
                const ushort_t* s = (g < 16) ? &h_u[(size_t)se[row] * H + g * 8]
                                             : &h_m[(size_t)de[row] * H + (g - 16) * 8];
                *(uint4*)(Ab + row * 768 + ((g ^ (row & 7)) << 4)) = *(const uint4*)s;
            } else {
                int c = (g - 32) * 8;
                float a0 = ea[(size_t)(e0 + row) * 2], a1 = ea[(size_t)(e0 + row) * 2 + 1];
                float4 w0a = *(const float4*)&ew[c];
                float4 w0b = *(const float4*)&ew[c + 4];
                float4 w1a = *(const float4*)&ew[H + c];
                float4 w1b = *(const float4*)&ew[H + c + 4];
                float4 bba = *(const float4*)&ebias[c];
                float4 bbb = *(const float4*)&ebias[c + 4];
                float v[8];
                v[0] = fmaxf(fmaf(a0, w0a.x, fmaf(a1, w1a.x, bba.x)), 0.f);
                v[1] = fmaxf(fmaf(a0, w0a.y, fmaf(a1, w1a.y, bba.y)), 0.f);
                v[2] = fmaxf(fmaf(a0, w0a.z, fmaf(a1, w1a.z, bba.z)), 0.f);
                v[3] = fmaxf(fmaf(a0, w0a.w, fmaf(a1, w1a.w, bba.w)), 0.f);
                v[4] = fmaxf(fmaf(a0, w0b.x, fmaf(a1, w1b.x, bbb.x)), 0.f);
                v[5] = fmaxf(fmaf(a0, w0b.y, fmaf(a1, w1b.y, bbb.y)), 0.f);
                v[6] = fmaxf(fmaf(a0, w0b.z, fmaf(a1, w1b.z, bbb.z)), 0.f);
                v[7] = fmaxf(fmaf(a0, w0b.w, fmaf(a1, w1b.w, bbb.w)), 0.f);
                union { ushort_t u[8]; uint4 q; } pk;
#pragma unroll
                for (int j = 0; j < 8; j++) pk.u[j] = f2bf(v[j]);
                *(uint4*)(Ab + row * 768 + ((g ^ (row & 7)) << 4)) = pk.q;
            }
        }
        __syncthreads();

        f32x4 acc[4][2];
#pragma unroll
        for (int rg = 0; rg < 4; rg++) {
            acc[rg][0] = (f32x4){bias0, bias0, bias0, bias0};
            acc[rg][1] = (f32x4){bias1, bias1, bias1, bias1};
        }
#pragma unroll
        for (int ks = 0; ks < 12; ks++) {
#pragma unroll
            for (int rg = 0; rg < 4; rg++) {
                int row = rg * 16 + l15;
                const bf16x8 a = *reinterpret_cast<const bf16x8*>(
                    Ab + row * 768 + (((ks * 4 + koff) ^ sw) << 4));
                acc[rg][0] = __builtin_amdgcn_mfma_f32_16x16x32_bf16(a, bf_[ks][0], acc[rg][0], 0, 0, 0);
                acc[rg][1] = __builtin_amdgcn_mfma_f32_16x16x32_bf16(a, bf_[ks][1], acc[rg][1], 0, 0, 0);
            }
        }

#pragma unroll
        for (int rg = 0; rg < 4; rg++) {
#pragma unroll
            for (int reg = 0; reg < 4; reg++) {
                float p = fmaxf(acc[rg][0][reg], 0.f) * c2v0 + fmaxf(acc[rg][1][reg], 0.f) * c2v1;
#pragma unroll
                for (int off = 8; off >= 1; off >>= 1) p += __shfl_xor(p, off, 64);
                if (l15 == 0) part[w * ET + rg * 16 + koff * 4 + reg] = p;
            }
        }
        __syncthreads();
        if (t < ET) {
            out[e0 + t] = part[t] + part[ET + t] + part[2 * ET + t] + part[3 * ET + t] + bias2;
        }
        __syncthreads();  // As/se/de/part reads done before next tile overwrites
    }
}

extern "C" void kernel_launch(void* const* d_in, const int* in_sizes, int n_in,
                              void* d_out, int out_size, void* d_ws, size_t ws_size,
                              hipStream_t stream) {
    const float* user_x     = (const float*)d_in[0];
    const float* merchant_x = (const float*)d_in[1];
    const float* edge_attr  = (const float*)d_in[2];
    const float* user_w     = (const float*)d_in[3];
    const float* user_b     = (const float*)d_in[4];
    const float* merch_w    = (const float*)d_in[5];
    const float* merch_b    = (const float*)d_in[6];
    const float* edge_w     = (const float*)d_in[7];
    const float* edge_b     = (const float*)d_in[8];
    const float* u2m_wl     = (const float*)d_in[9];
    const float* u2m_bl     = (const float*)d_in[10];
    const float* u2m_wr     = (const float*)d_in[11];
    const float* m2u_wl     = (const float*)d_in[12];
    const float* m2u_bl     = (const float*)d_in[13];
    const float* m2u_wr     = (const float*)d_in[14];
    const float* c1w        = (const float*)d_in[15];
    const float* c1b        = (const float*)d_in[16];
    const float* c2w        = (const float*)d_in[17];
    const float* c2b        = (const float*)d_in[18];
    const int*   ei         = (const int*)d_in[19];
    float* out = (float*)d_out;

    ushort_t* hu   = (ushort_t*)d_ws;
    ushort_t* hm   = hu  + (size_t)NU * H;
    ushort_t* hu2  = hm  + (size_t)NM * H;
    ushort_t* hm2  = hu2 + (size_t)NU * H;
    ushort_t* c1wT = hm2 + (size_t)NM * H;
    ushort_t* wTc  = c1wT + 384 * 128;
    int* rpu = (int*)(wTc + 4 * 128 * 256);
    int* rpm = rpu + (NU + 1);
    int* cu  = rpm + (NM + 1);
    int* cm  = cu + NU;
    int* eu  = cm + NM;
    int* em  = eu + NE;
    int* bsum_u = em + NE;
    int* boff_u = bsum_u + 128;
    int* bsum_m = boff_u + 128;
    int* boff_m = bsum_m + 128;

    const int NBU = (NU + 2047) / 2048;
    const int NBM = (NM + 2047) / 2048;

    hipMemsetAsync(cu, 0, (size_t)(NU + NM) * sizeof(int), stream);

    encode_bf16_kernel<<<(NU * 16 + 255) / 256, 256, 0, stream>>>(user_x, user_w, user_b, hu, NU, 3);
    encode_bf16_kernel<<<(NM * 16 + 255) / 256, 256, 0, stream>>>(merchant_x, merch_w, merch_b, hm, NM, 2);
    convert_w_kernel<<<(384 * 128 + 255) / 256, 256, 0, stream>>>(c1w, c1wT);
    for (int l = 0; l < 2; l++) {
        convert_conv_w_kernel<<<128, 256, 0, stream>>>(
            u2m_wl + (size_t)l * H * H, u2m_wr + (size_t)l * H * H, wTc + (size_t)l * 128 * 256);
        convert_conv_w_kernel<<<128, 256, 0, stream>>>(
            m2u_wl + (size_t)l * H * H, m2u_wr + (size_t)l * H * H, wTc + (size_t)(2 + l) * 128 * 256);
    }

    count_kernel<<<(NE + 255) / 256, 256, 0, stream>>>(ei, cu, cm, NE);
    scanA_kernel<<<NBU, 256, 0, stream>>>(cu, bsum_u, NU);
    scanB_kernel<<<1, 256, 0, stream>>>(bsum_u, boff_u, NBU, rpu + NU);
    scanC_kernel<<<NBU, 256, 0, stream>>>(cu, boff_u, rpu, NU);
    scanA_kernel<<<NBM, 256, 0, stream>>>(cm, bsum_m, NM);
    scanB_kernel<<<1, 256, 0, stream>>>(bsum_m, boff_m, NBM, rpm + NM);
    scanC_kernel<<<NBM, 256, 0, stream>>>(cm, boff_m, rpm, NM);
    hipMemsetAsync(cu, 0, (size_t)(NU + NM) * sizeof(int), stream);
    fill_kernel<<<(NE + 255) / 256, 256, 0, stream>>>(ei, rpu, rpm, cu, cm, eu, em, NE);

    const int CONV_TILES_M = (NM + 63) / 64;   // 782
    const int CONV_TILES_U = (NU + 63) / 64;   // 3125
    const int CONV_GRID_M  = CONV_TILES_M;     // < 1280, one tile each
    const int CONV_GRID_U  = 1280;             // 5 blocks/CU resident @ 32KB LDS

    const ushort_t* pu = hu; const ushort_t* pm = hm;
    ushort_t* qu = hu2; ushort_t* qm = hm2;
    for (int l = 0; l < 2; l++) {
        agg_bf16_kernel<<<(NM + 3) / 4, 256, 0, stream>>>(pu, rpm, em, qm, NM);
        agg_bf16_kernel<<<(NU + 3) / 4, 256, 0, stream>>>(pm, rpu, eu, qu, NU);
        conv_mfma_kernel<<<CONV_GRID_M, 256, 0, stream>>>(
            qm, pm, wTc + (size_t)l * 128 * 256, u2m_bl + (size_t)l * H, qm, NM, CONV_TILES_M);
        conv_mfma_kernel<<<CONV_GRID_U, 256, 0, stream>>>(
            qu, pu, wTc + (size_t)(2 + l) * 128 * 256, m2u_bl + (size_t)l * H, qu, NU, CONV_TILES_U);
        const ushort_t* tu = pu; pu = qu; qu = (ushort_t*)tu;
        const ushort_t* tm = pm; pm = qm; qm = (ushort_t*)tm;
    }

    const int EDGE_TILES = NE / 64;   // 9375
    edge_mlp_mfma_kernel<<<768, 256, 0, stream>>>(pu, pm, edge_attr, edge_w, edge_b,
                                                  c1wT, c1b, c2w, c2b, ei, out, EDGE_TILES);
}

// Round 8
// 727.085 us; speedup vs baseline: 1.5786x; 1.4576x over previous
//
#include <hip/hip_runtime.h>

#define H   128
#define NU  200000
#define NM  50000
#define NE  600000

typedef __attribute__((ext_vector_type(8))) short bf16x8;
typedef __attribute__((ext_vector_type(4))) float f32x4;
typedef unsigned short ushort_t;
typedef unsigned int uint_t;

__device__ __forceinline__ ushort_t f2bf(float x) {
    uint_t b = __float_as_uint(x);
    return (ushort_t)((b + 0x7FFF + ((b >> 16) & 1)) >> 16);  // RNE
}

// async 16B global->LDS. lds base must be wave-uniform; HW scatters lane l -> base + l*16.
__device__ __forceinline__ void gload16(const void* gsrc, void* lds_base) {
    __builtin_amdgcn_global_load_lds(
        (const __attribute__((address_space(1))) unsigned int*)gsrc,
        (__attribute__((address_space(3))) unsigned int*)lds_base,
        16, 0, 0);
}

// ---------------- encoders: h = bf16(relu(x @ W + b)), K small ----------------
__global__ void __launch_bounds__(256)
encode_bf16_kernel(const float* __restrict__ x, const float* __restrict__ W,
                   const float* __restrict__ b, ushort_t* __restrict__ h,
                   int n, int K) {
    int idx = blockIdx.x * 256 + threadIdx.x;
    if (idx >= n * 16) return;
    int r = idx >> 4, c0 = (idx & 15) * 8;
    float4 ba = *(const float4*)&b[c0], bb = *(const float4*)&b[c0 + 4];
    float acc[8] = {ba.x, ba.y, ba.z, ba.w, bb.x, bb.y, bb.z, bb.w};
    for (int k = 0; k < K; k++) {
        float xv = x[r * K + k];
        float4 wa = *(const float4*)&W[k * H + c0], wb = *(const float4*)&W[k * H + c0 + 4];
        acc[0] = fmaf(xv, wa.x, acc[0]); acc[1] = fmaf(xv, wa.y, acc[1]);
        acc[2] = fmaf(xv, wa.z, acc[2]); acc[3] = fmaf(xv, wa.w, acc[3]);
        acc[4] = fmaf(xv, wb.x, acc[4]); acc[5] = fmaf(xv, wb.y, acc[5]);
        acc[6] = fmaf(xv, wb.z, acc[6]); acc[7] = fmaf(xv, wb.w, acc[7]);
    }
    union { ushort_t u[8]; uint4 q; } pk;
#pragma unroll
    for (int j = 0; j < 8; j++) pk.u[j] = f2bf(fmaxf(acc[j], 0.f));
    *(uint4*)&h[(size_t)r * H + c0] = pk.q;
}

// ---------------- CSR build ----------------
__global__ void count_kernel(const int* __restrict__ ei, int* cu, int* cm, int n) {
    int e = blockIdx.x * blockDim.x + threadIdx.x;
    if (e >= n) return;
    atomicAdd(&cu[ei[e]], 1);
    atomicAdd(&cm[ei[NE + e]], 1);
}

__global__ void __launch_bounds__(256)
scanA_kernel(const int* __restrict__ cnt, int* __restrict__ bsum, int n) {
    __shared__ int s[256];
    int b = blockIdx.x, t = threadIdx.x;
    int base = b * 2048 + t * 8;
    int sum = 0;
    if (base + 8 <= n) {
        int4 a = *(const int4*)&cnt[base];
        int4 c = *(const int4*)&cnt[base + 4];
        sum = a.x + a.y + a.z + a.w + c.x + c.y + c.z + c.w;
    } else {
        for (int j = 0; j < 8; j++) { int i = base + j; if (i < n) sum += cnt[i]; }
    }
    s[t] = sum;
    __syncthreads();
    for (int off = 128; off >= 1; off >>= 1) {
        if (t < off) s[t] += s[t + off];
        __syncthreads();
    }
    if (t == 0) bsum[b] = s[0];
}

__global__ void __launch_bounds__(256)
scanB_kernel(const int* __restrict__ bsum, int* __restrict__ boff, int nb,
             int* __restrict__ rp_total) {
    __shared__ int s[256];
    int t = threadIdx.x;
    int v = (t < nb) ? bsum[t] : 0;
    s[t] = v;
    __syncthreads();
    for (int off = 1; off < 256; off <<= 1) {
        int x = (t >= off) ? s[t - off] : 0;
        __syncthreads();
        s[t] += x;
        __syncthreads();
    }
    if (t < nb) boff[t] = s[t] - v;
    if (t == 255) rp_total[0] = s[255];
}

__global__ void __launch_bounds__(256)
scanC_kernel(const int* __restrict__ cnt, const int* __restrict__ boff,
             int* __restrict__ rp, int n) {
    __shared__ int s[256];
    int b = blockIdx.x, t = threadIdx.x;
    int base = b * 2048 + t * 8;
    int v[8];
    int sum = 0;
    if (base + 8 <= n) {
        int4 a = *(const int4*)&cnt[base];
        int4 c = *(const int4*)&cnt[base + 4];
        v[0] = a.x; v[1] = a.y; v[2] = a.z; v[3] = a.w;
        v[4] = c.x; v[5] = c.y; v[6] = c.z; v[7] = c.w;
#pragma unroll
        for (int j = 0; j < 8; j++) sum += v[j];
    } else {
#pragma unroll
        for (int j = 0; j < 8; j++) { int i = base + j; v[j] = (i < n) ? cnt[i] : 0; sum += v[j]; }
    }
    s[t] = sum;
    __syncthreads();
    for (int off = 1; off < 256; off <<= 1) {
        int x = (t >= off) ? s[t - off] : 0;
        __syncthreads();
        s[t] += x;
        __syncthreads();
    }
    int run = boff[b] + s[t] - sum;
    if (base + 8 <= n) {
        int o[8];
#pragma unroll
        for (int j = 0; j < 8; j++) { o[j] = run; run += v[j]; }
        *(int4*)&rp[base]     = make_int4(o[0], o[1], o[2], o[3]);
        *(int4*)&rp[base + 4] = make_int4(o[4], o[5], o[6], o[7]);
    } else {
#pragma unroll
        for (int j = 0; j < 8; j++) { int i = base + j; if (i < n) rp[i] = run; run += v[j]; }
    }
}

__global__ void fill_kernel(const int* __restrict__ ei, const int* __restrict__ rpu,
                            const int* __restrict__ rpm, int* cu, int* cm,
                            int* __restrict__ eu, int* __restrict__ em, int n) {
    int e = blockIdx.x * blockDim.x + threadIdx.x;
    if (e >= n) return;
    int s = ei[e], d = ei[NE + e];
    eu[rpu[s] + atomicAdd(&cu[s], 1)] = d;
    em[rpm[d] + atomicAdd(&cm[d], 1)] = s;
}

// ---------------- merged segment-mean (both directions), 1 wave per node ----------------
__global__ void __launch_bounds__(256)
agg_both_kernel(const ushort_t* __restrict__ pu, const ushort_t* __restrict__ pm,
                const int* __restrict__ rpu, const int* __restrict__ rpm,
                const int* __restrict__ eu, const int* __restrict__ em,
                ushort_t* __restrict__ qu, ushort_t* __restrict__ qm, int nbM) {
    int bid = blockIdx.x;
    const ushort_t* src; const int* rp; const int* nbl; ushort_t* dst; int node, n;
    if (bid < nbM) {          // merchant agg over user neighbors
        node = bid * 4 + (threadIdx.x >> 6); n = NM; src = pu; rp = rpm; nbl = em; dst = qm;
    } else {                  // user agg over merchant neighbors
        node = (bid - nbM) * 4 + (threadIdx.x >> 6); n = NU; src = pm; rp = rpu; nbl = eu; dst = qu;
    }
    if (node >= n) return;
    int lane = threadIdx.x & 63;
    int beg = rp[node], end = rp[node + 1];
    float a0 = 0.f, a1 = 0.f;
    for (int j = beg; j < end; j++) {
        uint_t v = *(const uint_t*)&src[(size_t)nbl[j] * H + lane * 2];
        a0 += __uint_as_float((v & 0xffffu) << 16);
        a1 += __uint_as_float(v & 0xffff0000u);
    }
    int deg = end - beg;
    float inv = 1.0f / (float)(deg > 1 ? deg : 1);
    uint_t r = (uint_t)f2bf(a0 * inv) | ((uint_t)f2bf(a1 * inv) << 16);
    *(uint_t*)&dst[(size_t)node * H + lane * 2] = r;
}

// ---------------- weight converters ----------------
__global__ void convert_w_kernel(const float* __restrict__ c1w, ushort_t* __restrict__ outT) {
    int i = blockIdx.x * 256 + threadIdx.x;
    if (i >= 384 * 128) return;
    int k = i >> 7, n = i & 127;
    outT[n * 384 + k] = f2bf(c1w[i]);
}

__global__ void convert_conv_w_kernel(const float* __restrict__ wl, const float* __restrict__ wr,
                                      ushort_t* __restrict__ outT) {
    int i = blockIdx.x * 256 + threadIdx.x;
    if (i >= 128 * 256) return;
    int col = i >> 8, k = i & 255;
    float v = (k < 128) ? wl[k * H + col] : wr[(k - 128) * H + col];
    outT[i] = f2bf(v);
}

// ---------------- SAGE conv via MFMA, both directions in one launch ----------------
// out = bf16(relu([agg|self] @ wT' + bl)). 64 nodes/tile, 4 waves.
// Staging via global_load_lds: linear LDS dest, swizzle applied on the GLOBAL source granule.
__global__ void __launch_bounds__(256)
conv_pair_kernel(const ushort_t* __restrict__ aggM, const ushort_t* __restrict__ selfM,
                 const ushort_t* __restrict__ wTm, const float* __restrict__ blm,
                 ushort_t* __restrict__ outM,
                 const ushort_t* __restrict__ aggU, const ushort_t* __restrict__ selfU,
                 const ushort_t* __restrict__ wTu, const float* __restrict__ blu,
                 ushort_t* __restrict__ outU, int ntM) {
    const ushort_t *agg, *self, *wT; const float* bl; ushort_t* out; int n, tile;
    if ((int)blockIdx.x < ntM) {
        tile = blockIdx.x; agg = aggM; self = selfM; wT = wTm; bl = blm; out = outM; n = NM;
    } else {
        tile = blockIdx.x - ntM; agg = aggU; self = selfU; wT = wTu; bl = blu; out = outU; n = NU;
    }
    int node0 = tile * 64;
    int t = threadIdx.x, lane = t & 63, w = t >> 6;
    int l15 = lane & 15, koff = lane >> 4;
    __shared__ ushort_t As[64 * 256];   // 32 KB, rows of 32 granules (512 B)
    char* Ab = (char*)As;

    // async staging: lane l of wave w at step it covers LDS slot lin = it*256 + t
    // row = lin>>5, p = lin&31 (linear dest); source granule g = p ^ (row&7)
#pragma unroll
    for (int it = 0; it < 8; it++) {
        int row = it * 8 + w * 2 + (lane >> 5);
        int node = node0 + row; if (node >= n) node = n - 1;
        int g = (lane & 31) ^ (row & 7);
        const ushort_t* src = (g < 16) ? &agg[(size_t)node * H + g * 8]
                                       : &self[(size_t)node * H + (g - 16) * 8];
        gload16(src, Ab + it * 4096 + w * 1024);
    }

    bf16x8 bw[8][2];
#pragma unroll
    for (int ks = 0; ks < 8; ks++)
#pragma unroll
        for (int n1 = 0; n1 < 2; n1++) {
            int col = w * 32 + n1 * 16 + l15;
            bw[ks][n1] = *reinterpret_cast<const bf16x8*>(&wT[col * 256 + ks * 32 + koff * 8]);
        }
    float bias0 = bl[w * 32 + l15];
    float bias1 = bl[w * 32 + 16 + l15];
    int sw = l15 & 7;
    __syncthreads();   // drains vmcnt (gload queue) + lgkm

    f32x4 acc[4][2];
#pragma unroll
    for (int rg = 0; rg < 4; rg++) {
        acc[rg][0] = (f32x4){bias0, bias0, bias0, bias0};
        acc[rg][1] = (f32x4){bias1, bias1, bias1, bias1};
    }
#pragma unroll
    for (int ks = 0; ks < 8; ks++) {
#pragma unroll
        for (int rg = 0; rg < 4; rg++) {
            int row = rg * 16 + l15;
            const bf16x8 a = *reinterpret_cast<const bf16x8*>(
                Ab + row * 512 + (((ks * 4 + koff) ^ sw) << 4));
            acc[rg][0] = __builtin_amdgcn_mfma_f32_16x16x32_bf16(a, bw[ks][0], acc[rg][0], 0, 0, 0);
            acc[rg][1] = __builtin_amdgcn_mfma_f32_16x16x32_bf16(a, bw[ks][1], acc[rg][1], 0, 0, 0);
        }
    }

#pragma unroll
    for (int rg = 0; rg < 4; rg++)
#pragma unroll
        for (int reg = 0; reg < 4; reg++) {
            int node = node0 + rg * 16 + koff * 4 + reg;
            if (node < n) {
                out[(size_t)node * H + w * 32 + l15]      = f2bf(fmaxf(acc[rg][0][reg], 0.f));
                out[(size_t)node * H + w * 32 + 16 + l15] = f2bf(fmaxf(acc[rg][1][reg], 0.f));
            }
        }
}

// ---------------- edge MLP via MFMA (ET=64, async gather staging) ----------------
// LDS: As1 [64][32 granules] = gathered hu|hm (linear dest, source-swizzled);
//      As2 [64][16 granules] = computed edge features (VALU overlaps the async loads).
__global__ void __launch_bounds__(256)
edge_mlp_mfma_kernel(const ushort_t* __restrict__ h_u, const ushort_t* __restrict__ h_m,
                     const float* __restrict__ ea, const float* __restrict__ ew,
                     const float* __restrict__ ebias,
                     const ushort_t* __restrict__ c1wT, const float* __restrict__ c1b,
                     const float* __restrict__ c2w, const float* __restrict__ c2b,
                     const int* __restrict__ ei, float* __restrict__ out) {
    const int ET = 64;
    int e0 = blockIdx.x * ET;
    int t = threadIdx.x;
    int lane = t & 63, w = t >> 6;
    int l15 = lane & 15, koff = lane >> 4;

    __shared__ ushort_t As1[ET * 256];  // 32 KB: k 0..255 (hu|hm)
    __shared__ ushort_t As2[ET * 128];  // 16 KB: k 256..383 (edge feats)
    __shared__ float part[4 * ET];
    __shared__ int se[ET], de[ET];
    char* Ab1 = (char*)As1;
    char* Ab2 = (char*)As2;

    if (t < ET) {
        se[t] = ei[e0 + t];
        de[t] = ei[NE + e0 + t];
    }
    __syncthreads();   // se/de visible before gather addressing

    // ---- async gather of hu/hm granules (8 x global_load_lds per thread) ----
#pragma unroll
    for (int it = 0; it < 8; it++) {
        int row = it * 8 + w * 2 + (lane >> 5);
        int g = (lane & 31) ^ (row & 7);
        const ushort_t* src = (g < 16) ? &h_u[(size_t)se[row] * H + g * 8]
                                       : &h_m[(size_t)de[row] * H + (g - 16) * 8];
        gload16(src, Ab1 + it * 4096 + w * 1024);
    }

    // ---- B slice (tile-local; overlaps async gather) ----
    bf16x8 bf_[12][2];
#pragma unroll
    for (int ks = 0; ks < 12; ks++)
#pragma unroll
        for (int n1 = 0; n1 < 2; n1++) {
            int col = w * 32 + n1 * 16 + l15;
            bf_[ks][n1] = *reinterpret_cast<const bf16x8*>(&c1wT[col * 384 + ks * 32 + koff * 8]);
        }

    // ---- edge-feature granules on VALU (overlaps async gather) ----
#pragma unroll
    for (int it = 0; it < 4; it++) {
        int lin = it * 256 + t;          // 64 rows x 16 granules
        int row = lin >> 4, g2 = lin & 15;
        int c = g2 * 8;
        float a0 = ea[(size_t)(e0 + row) * 2], a1 = ea[(size_t)(e0 + row) * 2 + 1];
        float4 w0a = *(const float4*)&ew[c];
        float4 w0b = *(const float4*)&ew[c + 4];
        float4 w1a = *(const float4*)&ew[H + c];
        float4 w1b = *(const float4*)&ew[H + c + 4];
        float4 bba = *(const float4*)&ebias[c];
        float4 bbb = *(const float4*)&ebias[c + 4];
        float v[8];
        v[0] = fmaxf(fmaf(a0, w0a.x, fmaf(a1, w1a.x, bba.x)), 0.f);
        v[1] = fmaxf(fmaf(a0, w0a.y, fmaf(a1, w1a.y, bba.y)), 0.f);
        v[2] = fmaxf(fmaf(a0, w0a.z, fmaf(a1, w1a.z, bba.z)), 0.f);
        v[3] = fmaxf(fmaf(a0, w0a.w, fmaf(a1, w1a.w, bba.w)), 0.f);
        v[4] = fmaxf(fmaf(a0, w0b.x, fmaf(a1, w1b.x, bbb.x)), 0.f);
        v[5] = fmaxf(fmaf(a0, w0b.y, fmaf(a1, w1b.y, bbb.y)), 0.f);
        v[6] = fmaxf(fmaf(a0, w0b.z, fmaf(a1, w1b.z, bbb.z)), 0.f);
        v[7] = fmaxf(fmaf(a0, w0b.w, fmaf(a1, w1b.w, bbb.w)), 0.f);
        union { ushort_t u[8]; uint4 q; } pk;
#pragma unroll
        for (int j = 0; j < 8; j++) pk.u[j] = f2bf(v[j]);
        *(uint4*)(Ab2 + row * 256 + ((g2 ^ (row & 7)) << 4)) = pk.q;
    }
    __syncthreads();   // drains gload vmcnt + LDS writes

    int sw = l15 & 7;
    float bias0 = c1b[w * 32 + l15];
    float bias1 = c1b[w * 32 + 16 + l15];
    f32x4 acc[4][2];
#pragma unroll
    for (int rg = 0; rg < 4; rg++) {
        acc[rg][0] = (f32x4){bias0, bias0, bias0, bias0};
        acc[rg][1] = (f32x4){bias1, bias1, bias1, bias1};
    }
#pragma unroll
    for (int ks = 0; ks < 12; ks++) {
#pragma unroll
        for (int rg = 0; rg < 4; rg++) {
            int row = rg * 16 + l15;
            const bf16x8 a = (ks < 8)
                ? *reinterpret_cast<const bf16x8*>(Ab1 + row * 512 + (((ks * 4 + koff) ^ sw) << 4))
                : *reinterpret_cast<const bf16x8*>(Ab2 + row * 256 + ((((ks - 8) * 4 + koff) ^ sw) << 4));
            acc[rg][0] = __builtin_amdgcn_mfma_f32_16x16x32_bf16(a, bf_[ks][0], acc[rg][0], 0, 0, 0);
            acc[rg][1] = __builtin_amdgcn_mfma_f32_16x16x32_bf16(a, bf_[ks][1], acc[rg][1], 0, 0, 0);
        }
    }

    float c2v0 = c2w[w * 32 + l15];
    float c2v1 = c2w[w * 32 + 16 + l15];
#pragma unroll
    for (int rg = 0; rg < 4; rg++) {
#pragma unroll
        for (int reg = 0; reg < 4; reg++) {
            float p = fmaxf(acc[rg][0][reg], 0.f) * c2v0 + fmaxf(acc[rg][1][reg], 0.f) * c2v1;
#pragma unroll
            for (int off = 8; off >= 1; off >>= 1) p += __shfl_xor(p, off, 64);
            if (l15 == 0) part[w * ET + rg * 16 + koff * 4 + reg] = p;
        }
    }
    __syncthreads();
    if (t < ET) {
        out[e0 + t] = part[t] + part[ET + t] + part[2 * ET + t] + part[3 * ET + t] + c2b[0];
    }
}

extern "C" void kernel_launch(void* const* d_in, const int* in_sizes, int n_in,
                              void* d_out, int out_size, void* d_ws, size_t ws_size,
                              hipStream_t stream) {
    const float* user_x     = (const float*)d_in[0];
    const float* merchant_x = (const float*)d_in[1];
    const float* edge_attr  = (const float*)d_in[2];
    const float* user_w     = (const float*)d_in[3];
    const float* user_b     = (const float*)d_in[4];
    const float* merch_w    = (const float*)d_in[5];
    const float* merch_b    = (const float*)d_in[6];
    const float* edge_w     = (const float*)d_in[7];
    const float* edge_b     = (const float*)d_in[8];
    const float* u2m_wl     = (const float*)d_in[9];
    const float* u2m_bl     = (const float*)d_in[10];
    const float* u2m_wr     = (const float*)d_in[11];
    const float* m2u_wl     = (const float*)d_in[12];
    const float* m2u_bl     = (const float*)d_in[13];
    const float* m2u_wr     = (const float*)d_in[14];
    const float* c1w        = (const float*)d_in[15];
    const float* c1b        = (const float*)d_in[16];
    const float* c2w        = (const float*)d_in[17];
    const float* c2b        = (const float*)d_in[18];
    const int*   ei         = (const int*)d_in[19];
    float* out = (float*)d_out;

    ushort_t* hu   = (ushort_t*)d_ws;
    ushort_t* hm   = hu  + (size_t)NU * H;
    ushort_t* hu2  = hm  + (size_t)NM * H;
    ushort_t* hm2  = hu2 + (size_t)NU * H;
    ushort_t* c1wT = hm2 + (size_t)NM * H;
    ushort_t* wTc  = c1wT + 384 * 128;
    int* rpu = (int*)(wTc + 4 * 128 * 256);
    int* rpm = rpu + (NU + 1);
    int* cu  = rpm + (NM + 1);
    int* cm  = cu + NU;
    int* eu  = cm + NM;
    int* em  = eu + NE;
    int* bsum_u = em + NE;
    int* boff_u = bsum_u + 128;
    int* bsum_m = boff_u + 128;
    int* boff_m = bsum_m + 128;

    const int NBU = (NU + 2047) / 2048;
    const int NBM = (NM + 2047) / 2048;

    hipMemsetAsync(cu, 0, (size_t)(NU + NM) * sizeof(int), stream);

    encode_bf16_kernel<<<(NU * 16 + 255) / 256, 256, 0, stream>>>(user_x, user_w, user_b, hu, NU, 3);
    encode_bf16_kernel<<<(NM * 16 + 255) / 256, 256, 0, stream>>>(merchant_x, merch_w, merch_b, hm, NM, 2);
    convert_w_kernel<<<(384 * 128 + 255) / 256, 256, 0, stream>>>(c1w, c1wT);
    for (int l = 0; l < 2; l++) {
        convert_conv_w_kernel<<<128, 256, 0, stream>>>(
            u2m_wl + (size_t)l * H * H, u2m_wr + (size_t)l * H * H, wTc + (size_t)l * 128 * 256);
        convert_conv_w_kernel<<<128, 256, 0, stream>>>(
            m2u_wl + (size_t)l * H * H, m2u_wr + (size_t)l * H * H, wTc + (size_t)(2 + l) * 128 * 256);
    }

    count_kernel<<<(NE + 255) / 256, 256, 0, stream>>>(ei, cu, cm, NE);
    scanA_kernel<<<NBU, 256, 0, stream>>>(cu, bsum_u, NU);
    scanB_kernel<<<1, 256, 0, stream>>>(bsum_u, boff_u, NBU, rpu + NU);
    scanC_kernel<<<NBU, 256, 0, stream>>>(cu, boff_u, rpu, NU);
    scanA_kernel<<<NBM, 256, 0, stream>>>(cm, bsum_m, NM);
    scanB_kernel<<<1, 256, 0, stream>>>(bsum_m, boff_m, NBM, rpm + NM);
    scanC_kernel<<<NBM, 256, 0, stream>>>(cm, boff_m, rpm, NM);
    hipMemsetAsync(cu, 0, (size_t)(NU + NM) * sizeof(int), stream);
    fill_kernel<<<(NE + 255) / 256, 256, 0, stream>>>(ei, rpu, rpm, cu, cm, eu, em, NE);

    const int AGG_NBM = (NM + 3) / 4;          // 12500
    const int AGG_NBU = (NU + 3) / 4;          // 50000
    const int CONV_TILES_M = (NM + 63) / 64;   // 782
    const int CONV_TILES_U = (NU + 63) / 64;   // 3125

    const ushort_t* pu = hu; const ushort_t* pm = hm;
    ushort_t* qu = hu2; ushort_t* qm = hm2;
    for (int l = 0; l < 2; l++) {
        agg_both_kernel<<<AGG_NBM + AGG_NBU, 256, 0, stream>>>(
            pu, pm, rpu, rpm, eu, em, qu, qm, AGG_NBM);
        conv_pair_kernel<<<CONV_TILES_M + CONV_TILES_U, 256, 0, stream>>>(
            qm, pm, wTc + (size_t)l * 128 * 256, u2m_bl + (size_t)l * H, qm,
            qu, pu, wTc + (size_t)(2 + l) * 128 * 256, m2u_bl + (size_t)l * H, qu,
            CONV_TILES_M);
        const ushort_t* tu = pu; pu = qu; qu = (ushort_t*)tu;
        const ushort_t* tm = pm; pm = qm; qm = (ushort_t*)tm;
    }

    edge_mlp_mfma_kernel<<<NE / 64, 256, 0, stream>>>(pu, pm, edge_attr, edge_w, edge_b,
                                                      c1wT, c1b, c2w, c2b, ei, out);
}

// Round 9
// 714.559 us; speedup vs baseline: 1.6063x; 1.0175x over previous
//
#include <hip/hip_runtime.h>

#define H   128
#define NU  200000
#define NM  50000
#define NE  600000

typedef __attribute__((ext_vector_type(8))) short bf16x8;
typedef __attribute__((ext_vector_type(4))) float f32x4;
typedef unsigned short ushort_t;
typedef unsigned int uint_t;

__device__ __forceinline__ ushort_t f2bf(float x) {
    uint_t b = __float_as_uint(x);
    return (ushort_t)((b + 0x7FFF + ((b >> 16) & 1)) >> 16);  // RNE
}

// async 16B global->LDS. lds base must be wave-uniform; HW scatters lane l -> base + l*16.
__device__ __forceinline__ void gload16(const void* gsrc, void* lds_base) {
    __builtin_amdgcn_global_load_lds(
        (const __attribute__((address_space(1))) unsigned int*)gsrc,
        (__attribute__((address_space(3))) unsigned int*)lds_base,
        16, 0, 0);
}

// ---------------- encoders: h = bf16(relu(x @ W + b)), K small ----------------
__global__ void __launch_bounds__(256)
encode_bf16_kernel(const float* __restrict__ x, const float* __restrict__ W,
                   const float* __restrict__ b, ushort_t* __restrict__ h,
                   int n, int K) {
    int idx = blockIdx.x * 256 + threadIdx.x;
    if (idx >= n * 16) return;
    int r = idx >> 4, c0 = (idx & 15) * 8;
    float4 ba = *(const float4*)&b[c0], bb = *(const float4*)&b[c0 + 4];
    float acc[8] = {ba.x, ba.y, ba.z, ba.w, bb.x, bb.y, bb.z, bb.w};
    for (int k = 0; k < K; k++) {
        float xv = x[r * K + k];
        float4 wa = *(const float4*)&W[k * H + c0], wb = *(const float4*)&W[k * H + c0 + 4];
        acc[0] = fmaf(xv, wa.x, acc[0]); acc[1] = fmaf(xv, wa.y, acc[1]);
        acc[2] = fmaf(xv, wa.z, acc[2]); acc[3] = fmaf(xv, wa.w, acc[3]);
        acc[4] = fmaf(xv, wb.x, acc[4]); acc[5] = fmaf(xv, wb.y, acc[5]);
        acc[6] = fmaf(xv, wb.z, acc[6]); acc[7] = fmaf(xv, wb.w, acc[7]);
    }
    union { ushort_t u[8]; uint4 q; } pk;
#pragma unroll
    for (int j = 0; j < 8; j++) pk.u[j] = f2bf(fmaxf(acc[j], 0.f));
    *(uint4*)&h[(size_t)r * H + c0] = pk.q;
}

// ---------------- CSR build ----------------
__global__ void count_kernel(const int* __restrict__ ei, int* cu, int* cm, int n) {
    int e = blockIdx.x * blockDim.x + threadIdx.x;
    if (e >= n) return;
    atomicAdd(&cu[ei[e]], 1);
    atomicAdd(&cm[ei[NE + e]], 1);
}

__global__ void __launch_bounds__(256)
scanA_kernel(const int* __restrict__ cnt, int* __restrict__ bsum, int n) {
    __shared__ int s[256];
    int b = blockIdx.x, t = threadIdx.x;
    int base = b * 2048 + t * 8;
    int sum = 0;
    if (base + 8 <= n) {
        int4 a = *(const int4*)&cnt[base];
        int4 c = *(const int4*)&cnt[base + 4];
        sum = a.x + a.y + a.z + a.w + c.x + c.y + c.z + c.w;
    } else {
        for (int j = 0; j < 8; j++) { int i = base + j; if (i < n) sum += cnt[i]; }
    }
    s[t] = sum;
    __syncthreads();
    for (int off = 128; off >= 1; off >>= 1) {
        if (t < off) s[t] += s[t + off];
        __syncthreads();
    }
    if (t == 0) bsum[b] = s[0];
}

__global__ void __launch_bounds__(256)
scanB_kernel(const int* __restrict__ bsum, int* __restrict__ boff, int nb,
             int* __restrict__ rp_total) {
    __shared__ int s[256];
    int t = threadIdx.x;
    int v = (t < nb) ? bsum[t] : 0;
    s[t] = v;
    __syncthreads();
    for (int off = 1; off < 256; off <<= 1) {
        int x = (t >= off) ? s[t - off] : 0;
        __syncthreads();
        s[t] += x;
        __syncthreads();
    }
    if (t < nb) boff[t] = s[t] - v;
    if (t == 255) rp_total[0] = s[255];
}

__global__ void __launch_bounds__(256)
scanC_kernel(const int* __restrict__ cnt, const int* __restrict__ boff,
             int* __restrict__ rp, int n) {
    __shared__ int s[256];
    int b = blockIdx.x, t = threadIdx.x;
    int base = b * 2048 + t * 8;
    int v[8];
    int sum = 0;
    if (base + 8 <= n) {
        int4 a = *(const int4*)&cnt[base];
        int4 c = *(const int4*)&cnt[base + 4];
        v[0] = a.x; v[1] = a.y; v[2] = a.z; v[3] = a.w;
        v[4] = c.x; v[5] = c.y; v[6] = c.z; v[7] = c.w;
#pragma unroll
        for (int j = 0; j < 8; j++) sum += v[j];
    } else {
#pragma unroll
        for (int j = 0; j < 8; j++) { int i = base + j; v[j] = (i < n) ? cnt[i] : 0; sum += v[j]; }
    }
    s[t] = sum;
    __syncthreads();
    for (int off = 1; off < 256; off <<= 1) {
        int x = (t >= off) ? s[t - off] : 0;
        __syncthreads();
        s[t] += x;
        __syncthreads();
    }
    int run = boff[b] + s[t] - sum;
    if (base + 8 <= n) {
        int o[8];
#pragma unroll
        for (int j = 0; j < 8; j++) { o[j] = run; run += v[j]; }
        *(int4*)&rp[base]     = make_int4(o[0], o[1], o[2], o[3]);
        *(int4*)&rp[base + 4] = make_int4(o[4], o[5], o[6], o[7]);
    } else {
#pragma unroll
        for (int j = 0; j < 8; j++) { int i = base + j; if (i < n) rp[i] = run; run += v[j]; }
    }
}

__global__ void fill_kernel(const int* __restrict__ ei, const int* __restrict__ rpu,
                            const int* __restrict__ rpm, int* cu, int* cm,
                            int* __restrict__ eu, int* __restrict__ em, int n) {
    int e = blockIdx.x * blockDim.x + threadIdx.x;
    if (e >= n) return;
    int s = ei[e], d = ei[NE + e];
    eu[rpu[s] + atomicAdd(&cu[s], 1)] = d;
    em[rpm[d] + atomicAdd(&cm[d], 1)] = s;
}

// ---------------- merged segment-mean (both directions), 1 wave per node ----------------
__global__ void __launch_bounds__(256)
agg_both_kernel(const ushort_t* __restrict__ pu, const ushort_t* __restrict__ pm,
                const int* __restrict__ rpu, const int* __restrict__ rpm,
                const int* __restrict__ eu, const int* __restrict__ em,
                ushort_t* __restrict__ qu, ushort_t* __restrict__ qm, int nbM) {
    int bid = blockIdx.x;
    const ushort_t* src; const int* rp; const int* nbl; ushort_t* dst; int node, n;
    if (bid < nbM) {
        node = bid * 4 + (threadIdx.x >> 6); n = NM; src = pu; rp = rpm; nbl = em; dst = qm;
    } else {
        node = (bid - nbM) * 4 + (threadIdx.x >> 6); n = NU; src = pm; rp = rpu; nbl = eu; dst = qu;
    }
    if (node >= n) return;
    int lane = threadIdx.x & 63;
    int beg = rp[node], end = rp[node + 1];
    float a0 = 0.f, a1 = 0.f;
    for (int j = beg; j < end; j++) {
        uint_t v = *(const uint_t*)&src[(size_t)nbl[j] * H + lane * 2];
        a0 += __uint_as_float((v & 0xffffu) << 16);
        a1 += __uint_as_float(v & 0xffff0000u);
    }
    int deg = end - beg;
    float inv = 1.0f / (float)(deg > 1 ? deg : 1);
    uint_t r = (uint_t)f2bf(a0 * inv) | ((uint_t)f2bf(a1 * inv) << 16);
    *(uint_t*)&dst[(size_t)node * H + lane * 2] = r;
}

// ---------------- weight converters ----------------
__global__ void convert_w_kernel(const float* __restrict__ c1w, ushort_t* __restrict__ outT) {
    int i = blockIdx.x * 256 + threadIdx.x;
    if (i >= 384 * 128) return;
    int k = i >> 7, n = i & 127;
    outT[n * 384 + k] = f2bf(c1w[i]);
}

__global__ void convert_conv_w_kernel(const float* __restrict__ wl, const float* __restrict__ wr,
                                      ushort_t* __restrict__ outT) {
    int i = blockIdx.x * 256 + threadIdx.x;
    if (i >= 128 * 256) return;
    int col = i >> 8, k = i & 255;
    float v = (k < 128) ? wl[k * H + col] : wr[(k - 128) * H + col];
    outT[i] = f2bf(v);
}

// ---------------- SAGE conv via MFMA, both directions, 8 waves x 16 cols ----------------
__global__ void __launch_bounds__(512)
conv_pair_kernel(const ushort_t* __restrict__ aggM, const ushort_t* __restrict__ selfM,
                 const ushort_t* __restrict__ wTm, const float* __restrict__ blm,
                 ushort_t* __restrict__ outM,
                 const ushort_t* __restrict__ aggU, const ushort_t* __restrict__ selfU,
                 const ushort_t* __restrict__ wTu, const float* __restrict__ blu,
                 ushort_t* __restrict__ outU, int ntM) {
    const ushort_t *agg, *self, *wT; const float* bl; ushort_t* out; int n, tile;
    if ((int)blockIdx.x < ntM) {
        tile = blockIdx.x; agg = aggM; self = selfM; wT = wTm; bl = blm; out = outM; n = NM;
    } else {
        tile = blockIdx.x - ntM; agg = aggU; self = selfU; wT = wTu; bl = blu; out = outU; n = NU;
    }
    int node0 = tile * 64;
    int t = threadIdx.x, lane = t & 63, w = t >> 6;   // w in 0..7
    int l15 = lane & 15, koff = lane >> 4;
    __shared__ ushort_t As[64 * 256];   // 32 KB, rows of 32 granules (512 B)
    char* Ab = (char*)As;

    // async staging: 4 rounds x 512 threads = 2048 granules (linear dest, source-swizzled)
#pragma unroll
    for (int it = 0; it < 4; it++) {
        int row = it * 16 + w * 2 + (lane >> 5);
        int node = node0 + row; if (node >= n) node = n - 1;
        int g = (lane & 31) ^ (row & 7);
        const ushort_t* src = (g < 16) ? &agg[(size_t)node * H + g * 8]
                                       : &self[(size_t)node * H + (g - 16) * 8];
        gload16(src, Ab + it * 8192 + w * 1024);
    }

    // B slice: wave w owns cols [16w, 16w+16)
    bf16x8 bw[8];
    int col = w * 16 + l15;
#pragma unroll
    for (int ks = 0; ks < 8; ks++)
        bw[ks] = *reinterpret_cast<const bf16x8*>(&wT[col * 256 + ks * 32 + koff * 8]);
    float bias0 = bl[col];
    int sw = l15 & 7;
    __syncthreads();   // drains gload vmcnt

    f32x4 acc[4];
#pragma unroll
    for (int rg = 0; rg < 4; rg++) acc[rg] = (f32x4){bias0, bias0, bias0, bias0};
#pragma unroll
    for (int ks = 0; ks < 8; ks++) {
#pragma unroll
        for (int rg = 0; rg < 4; rg++) {
            int row = rg * 16 + l15;
            const bf16x8 a = *reinterpret_cast<const bf16x8*>(
                Ab + row * 512 + (((ks * 4 + koff) ^ sw) << 4));
            acc[rg] = __builtin_amdgcn_mfma_f32_16x16x32_bf16(a, bw[ks], acc[rg], 0, 0, 0);
        }
    }

#pragma unroll
    for (int rg = 0; rg < 4; rg++)
#pragma unroll
        for (int reg = 0; reg < 4; reg++) {
            int node = node0 + rg * 16 + koff * 4 + reg;
            if (node < n)
                out[(size_t)node * H + col] = f2bf(fmaxf(acc[rg][reg], 0.f));
        }
}

// ---------------- edge MLP via MFMA (ET=64, 8 waves x 16 cols, async staging) ----------------
__global__ void __launch_bounds__(512)
edge_mlp_mfma_kernel(const ushort_t* __restrict__ h_u, const ushort_t* __restrict__ h_m,
                     const float* __restrict__ ea, const float* __restrict__ ew,
                     const float* __restrict__ ebias,
                     const ushort_t* __restrict__ c1wT, const float* __restrict__ c1b,
                     const float* __restrict__ c2w, const float* __restrict__ c2b,
                     const int* __restrict__ ei, float* __restrict__ out) {
    const int ET = 64;
    int e0 = blockIdx.x * ET;
    int t = threadIdx.x;
    int lane = t & 63, w = t >> 6;   // w in 0..7
    int l15 = lane & 15, koff = lane >> 4;

    __shared__ ushort_t As1[ET * 256];  // 32 KB: k 0..255 (hu|hm)
    __shared__ ushort_t As2[ET * 128];  // 16 KB: k 256..383 (edge feats)
    __shared__ float part[8 * ET];      // 2 KB
    __shared__ int se[ET], de[ET];
    char* Ab1 = (char*)As1;
    char* Ab2 = (char*)As2;

    if (t < ET) {
        se[t] = ei[e0 + t];
        de[t] = ei[NE + e0 + t];
    }
    __syncthreads();   // se/de visible before gather addressing

    // ---- async gather of hu/hm granules: 4 rounds x 512 threads = 2048 granules ----
#pragma unroll
    for (int it = 0; it < 4; it++) {
        int row = it * 16 + w * 2 + (lane >> 5);
        int g = (lane & 31) ^ (row & 7);
        const ushort_t* src = (g < 16) ? &h_u[(size_t)se[row] * H + g * 8]
                                       : &h_m[(size_t)de[row] * H + (g - 16) * 8];
        gload16(src, Ab1 + it * 8192 + w * 1024);
    }

    // ---- B slice: wave w owns cols [16w, 16w+16) (overlaps async gather) ----
    bf16x8 bf_[12];
    int col = w * 16 + l15;
#pragma unroll
    for (int ks = 0; ks < 12; ks++)
        bf_[ks] = *reinterpret_cast<const bf16x8*>(&c1wT[col * 384 + ks * 32 + koff * 8]);

    // ---- edge-feature granules on VALU (overlaps async gather) ----
#pragma unroll
    for (int it = 0; it < 2; it++) {
        int lin = it * 512 + t;          // 0..1023 = 64 rows x 16 granules
        int row = lin >> 4, g2 = lin & 15;
        int c = g2 * 8;
        float a0 = ea[(size_t)(e0 + row) * 2], a1 = ea[(size_t)(e0 + row) * 2 + 1];
        float4 w0a = *(const float4*)&ew[c];
        float4 w0b = *(const float4*)&ew[c + 4];
        float4 w1a = *(const float4*)&ew[H + c];
        float4 w1b = *(const float4*)&ew[H + c + 4];
        float4 bba = *(const float4*)&ebias[c];
        float4 bbb = *(const float4*)&ebias[c + 4];
        float v[8];
        v[0] = fmaxf(fmaf(a0, w0a.x, fmaf(a1, w1a.x, bba.x)), 0.f);
        v[1] = fmaxf(fmaf(a0, w0a.y, fmaf(a1, w1a.y, bba.y)), 0.f);
        v[2] = fmaxf(fmaf(a0, w0a.z, fmaf(a1, w1a.z, bba.z)), 0.f);
        v[3] = fmaxf(fmaf(a0, w0a.w, fmaf(a1, w1a.w, bba.w)), 0.f);
        v[4] = fmaxf(fmaf(a0, w0b.x, fmaf(a1, w1b.x, bbb.x)), 0.f);
        v[5] = fmaxf(fmaf(a0, w0b.y, fmaf(a1, w1b.y, bbb.y)), 0.f);
        v[6] = fmaxf(fmaf(a0, w0b.z, fmaf(a1, w1b.z, bbb.z)), 0.f);
        v[7] = fmaxf(fmaf(a0, w0b.w, fmaf(a1, w1b.w, bbb.w)), 0.f);
        union { ushort_t u[8]; uint4 q; } pk;
#pragma unroll
        for (int j = 0; j < 8; j++) pk.u[j] = f2bf(v[j]);
        *(uint4*)(Ab2 + row * 256 + ((g2 ^ (row & 7)) << 4)) = pk.q;
    }
    __syncthreads();   // drains gload vmcnt + LDS writes

    int sw = l15 & 7;
    float bias0 = c1b[col];
    f32x4 acc[4];
#pragma unroll
    for (int rg = 0; rg < 4; rg++) acc[rg] = (f32x4){bias0, bias0, bias0, bias0};
#pragma unroll
    for (int ks = 0; ks < 12; ks++) {
#pragma unroll
        for (int rg = 0; rg < 4; rg++) {
            int row = rg * 16 + l15;
            const bf16x8 a = (ks < 8)
                ? *reinterpret_cast<const bf16x8*>(Ab1 + row * 512 + (((ks * 4 + koff) ^ sw) << 4))
                : *reinterpret_cast<const bf16x8*>(Ab2 + row * 256 + ((((ks - 8) * 4 + koff) ^ sw) << 4));
            acc[rg] = __builtin_amdgcn_mfma_f32_16x16x32_bf16(a, bf_[ks], acc[rg], 0, 0, 0);
        }
    }

    float c2v = c2w[col];
#pragma unroll
    for (int rg = 0; rg < 4; rg++) {
#pragma unroll
        for (int reg = 0; reg < 4; reg++) {
            float p = fmaxf(acc[rg][reg], 0.f) * c2v;
#pragma unroll
            for (int off = 8; off >= 1; off >>= 1) p += __shfl_xor(p, off, 64);
            if (l15 == 0) part[w * ET + rg * 16 + koff * 4 + reg] = p;
        }
    }
    __syncthreads();
    if (t < ET) {
        float s = part[t];
#pragma unroll
        for (int ww = 1; ww < 8; ww++) s += part[ww * ET + t];
        out[e0 + t] = s + c2b[0];
    }
}

extern "C" void kernel_launch(void* const* d_in, const int* in_sizes, int n_in,
                              void* d_out, int out_size, void* d_ws, size_t ws_size,
                              hipStream_t stream) {
    const float* user_x     = (const float*)d_in[0];
    const float* merchant_x = (const float*)d_in[1];
    const float* edge_attr  = (const float*)d_in[2];
    const float* user_w     = (const float*)d_in[3];
    const float* user_b     = (const float*)d_in[4];
    const float* merch_w    = (const float*)d_in[5];
    const float* merch_b    = (const float*)d_in[6];
    const float* edge_w     = (const float*)d_in[7];
    const float* edge_b     = (const float*)d_in[8];
    const float* u2m_wl     = (const float*)d_in[9];
    const float* u2m_bl     = (const float*)d_in[10];
    const float* u2m_wr     = (const float*)d_in[11];
    const float* m2u_wl     = (const float*)d_in[12];
    const float* m2u_bl     = (const float*)d_in[13];
    const float* m2u_wr     = (const float*)d_in[14];
    const float* c1w        = (const float*)d_in[15];
    const float* c1b        = (const float*)d_in[16];
    const float* c2w        = (const float*)d_in[17];
    const float* c2b        = (const float*)d_in[18];
    const int*   ei         = (const int*)d_in[19];
    float* out = (float*)d_out;

    ushort_t* hu   = (ushort_t*)d_ws;
    ushort_t* hm   = hu  + (size_t)NU * H;
    ushort_t* hu2  = hm  + (size_t)NM * H;
    ushort_t* hm2  = hu2 + (size_t)NU * H;
    ushort_t* c1wT = hm2 + (size_t)NM * H;
    ushort_t* wTc  = c1wT + 384 * 128;
    int* rpu = (int*)(wTc + 4 * 128 * 256);
    int* rpm = rpu + (NU + 1);
    int* cu  = rpm + (NM + 1);
    int* cm  = cu + NU;
    int* eu  = cm + NM;
    int* em  = eu + NE;
    int* bsum_u = em + NE;
    int* boff_u = bsum_u + 128;
    int* bsum_m = boff_u + 128;
    int* boff_m = bsum_m + 128;

    const int NBU = (NU + 2047) / 2048;
    const int NBM = (NM + 2047) / 2048;

    hipMemsetAsync(cu, 0, (size_t)(NU + NM) * sizeof(int), stream);

    encode_bf16_kernel<<<(NU * 16 + 255) / 256, 256, 0, stream>>>(user_x, user_w, user_b, hu, NU, 3);
    encode_bf16_kernel<<<(NM * 16 + 255) / 256, 256, 0, stream>>>(merchant_x, merch_w, merch_b, hm, NM, 2);
    convert_w_kernel<<<(384 * 128 + 255) / 256, 256, 0, stream>>>(c1w, c1wT);
    for (int l = 0; l < 2; l++) {
        convert_conv_w_kernel<<<128, 256, 0, stream>>>(
            u2m_wl + (size_t)l * H * H, u2m_wr + (size_t)l * H * H, wTc + (size_t)l * 128 * 256);
        convert_conv_w_kernel<<<128, 256, 0, stream>>>(
            m2u_wl + (size_t)l * H * H, m2u_wr + (size_t)l * H * H, wTc + (size_t)(2 + l) * 128 * 256);
    }

    count_kernel<<<(NE + 255) / 256, 256, 0, stream>>>(ei, cu, cm, NE);
    scanA_kernel<<<NBU, 256, 0, stream>>>(cu, bsum_u, NU);
    scanB_kernel<<<1, 256, 0, stream>>>(bsum_u, boff_u, NBU, rpu + NU);
    scanC_kernel<<<NBU, 256, 0, stream>>>(cu, boff_u, rpu, NU);
    scanA_kernel<<<NBM, 256, 0, stream>>>(cm, bsum_m, NM);
    scanB_kernel<<<1, 256, 0, stream>>>(bsum_m, boff_m, NBM, rpm + NM);
    scanC_kernel<<<NBM, 256, 0, stream>>>(cm, boff_m, rpm, NM);
    hipMemsetAsync(cu, 0, (size_t)(NU + NM) * sizeof(int), stream);
    fill_kernel<<<(NE + 255) / 256, 256, 0, stream>>>(ei, rpu, rpm, cu, cm, eu, em, NE);

    const int AGG_NBM = (NM + 3) / 4;          // 12500
    const int AGG_NBU = (NU + 3) / 4;          // 50000
    const int CONV_TILES_M = (NM + 63) / 64;   // 782
    const int CONV_TILES_U = (NU + 63) / 64;   // 3125

    const ushort_t* pu = hu; const ushort_t* pm = hm;
    ushort_t* qu = hu2; ushort_t* qm = hm2;
    for (int l = 0; l < 2; l++) {
        agg_both_kernel<<<AGG_NBM + AGG_NBU, 256, 0, stream>>>(
            pu, pm, rpu, rpm, eu, em, qu, qm, AGG_NBM);
        conv_pair_kernel<<<CONV_TILES_M + CONV_TILES_U, 512, 0, stream>>>(
            qm, pm, wTc + (size_t)l * 128 * 256, u2m_bl + (size_t)l * H, qm,
            qu, pu, wTc + (size_t)(2 + l) * 128 * 256, m2u_bl + (size_t)l * H, qu,
            CONV_TILES_M);
        const ushort_t* tu = pu; pu = qu; qu = (ushort_t*)tu;
        const ushort_t* tm = pm; pm = qm; qm = (ushort_t*)tm;
    }

    edge_mlp_mfma_kernel<<<NE / 64, 512, 0, stream>>>(pu, pm, edge_attr, edge_w, edge_b,
                                                      c1wT, c1b, c2w, c2b, ei, out);
}

// Round 10
// 629.243 us; speedup vs baseline: 1.8241x; 1.1356x over previous
//
#include <hip/hip_runtime.h>

#define H   128
#define NU  200000
#define NM  50000
#define NE  600000

typedef __attribute__((ext_vector_type(8))) short bf16x8;
typedef __attribute__((ext_vector_type(4))) float f32x4;
typedef unsigned short ushort_t;
typedef unsigned int uint_t;

__device__ __forceinline__ ushort_t f2bf(float x) {
    uint_t b = __float_as_uint(x);
    return (ushort_t)((b + 0x7FFF + ((b >> 16) & 1)) >> 16);  // RNE
}

// async 16B global->LDS. lds base must be wave-uniform; HW scatters lane l -> base + l*16.
__device__ __forceinline__ void gload16(const void* gsrc, void* lds_base) {
    __builtin_amdgcn_global_load_lds(
        (const __attribute__((address_space(1))) unsigned int*)gsrc,
        (__attribute__((address_space(3))) unsigned int*)lds_base,
        16, 0, 0);
}

// ---------------- encoders: h = bf16(relu(x @ W + b)), K small ----------------
__global__ void __launch_bounds__(256)
encode_bf16_kernel(const float* __restrict__ x, const float* __restrict__ W,
                   const float* __restrict__ b, ushort_t* __restrict__ h,
                   int n, int K) {
    int idx = blockIdx.x * 256 + threadIdx.x;
    if (idx >= n * 16) return;
    int r = idx >> 4, c0 = (idx & 15) * 8;
    float4 ba = *(const float4*)&b[c0], bb = *(const float4*)&b[c0 + 4];
    float acc[8] = {ba.x, ba.y, ba.z, ba.w, bb.x, bb.y, bb.z, bb.w};
    for (int k = 0; k < K; k++) {
        float xv = x[r * K + k];
        float4 wa = *(const float4*)&W[k * H + c0], wb = *(const float4*)&W[k * H + c0 + 4];
        acc[0] = fmaf(xv, wa.x, acc[0]); acc[1] = fmaf(xv, wa.y, acc[1]);
        acc[2] = fmaf(xv, wa.z, acc[2]); acc[3] = fmaf(xv, wa.w, acc[3]);
        acc[4] = fmaf(xv, wb.x, acc[4]); acc[5] = fmaf(xv, wb.y, acc[5]);
        acc[6] = fmaf(xv, wb.z, acc[6]); acc[7] = fmaf(xv, wb.w, acc[7]);
    }
    union { ushort_t u[8]; uint4 q; } pk;
#pragma unroll
    for (int j = 0; j < 8; j++) pk.u[j] = f2bf(fmaxf(acc[j], 0.f));
    *(uint4*)&h[(size_t)r * H + c0] = pk.q;
}

// ---------------- CSR build ----------------
__global__ void count_kernel(const int* __restrict__ ei, int* cu, int* cm, int n) {
    int e = blockIdx.x * blockDim.x + threadIdx.x;
    if (e >= n) return;
    atomicAdd(&cu[ei[e]], 1);
    atomicAdd(&cm[ei[NE + e]], 1);
}

__global__ void __launch_bounds__(256)
scanA_kernel(const int* __restrict__ cnt, int* __restrict__ bsum, int n) {
    __shared__ int s[256];
    int b = blockIdx.x, t = threadIdx.x;
    int base = b * 2048 + t * 8;
    int sum = 0;
    if (base + 8 <= n) {
        int4 a = *(const int4*)&cnt[base];
        int4 c = *(const int4*)&cnt[base + 4];
        sum = a.x + a.y + a.z + a.w + c.x + c.y + c.z + c.w;
    } else {
        for (int j = 0; j < 8; j++) { int i = base + j; if (i < n) sum += cnt[i]; }
    }
    s[t] = sum;
    __syncthreads();
    for (int off = 128; off >= 1; off >>= 1) {
        if (t < off) s[t] += s[t + off];
        __syncthreads();
    }
    if (t == 0) bsum[b] = s[0];
}

__global__ void __launch_bounds__(256)
scanB_kernel(const int* __restrict__ bsum, int* __restrict__ boff, int nb,
             int* __restrict__ rp_total) {
    __shared__ int s[256];
    int t = threadIdx.x;
    int v = (t < nb) ? bsum[t] : 0;
    s[t] = v;
    __syncthreads();
    for (int off = 1; off < 256; off <<= 1) {
        int x = (t >= off) ? s[t - off] : 0;
        __syncthreads();
        s[t] += x;
        __syncthreads();
    }
    if (t < nb) boff[t] = s[t] - v;
    if (t == 255) rp_total[0] = s[255];
}

__global__ void __launch_bounds__(256)
scanC_kernel(const int* __restrict__ cnt, const int* __restrict__ boff,
             int* __restrict__ rp, int n) {
    __shared__ int s[256];
    int b = blockIdx.x, t = threadIdx.x;
    int base = b * 2048 + t * 8;
    int v[8];
    int sum = 0;
    if (base + 8 <= n) {
        int4 a = *(const int4*)&cnt[base];
        int4 c = *(const int4*)&cnt[base + 4];
        v[0] = a.x; v[1] = a.y; v[2] = a.z; v[3] = a.w;
        v[4] = c.x; v[5] = c.y; v[6] = c.z; v[7] = c.w;
#pragma unroll
        for (int j = 0; j < 8; j++) sum += v[j];
    } else {
#pragma unroll
        for (int j = 0; j < 8; j++) { int i = base + j; v[j] = (i < n) ? cnt[i] : 0; sum += v[j]; }
    }
    s[t] = sum;
    __syncthreads();
    for (int off = 1; off < 256; off <<= 1) {
        int x = (t >= off) ? s[t - off] : 0;
        __syncthreads();
        s[t] += x;
        __syncthreads();
    }
    int run = boff[b] + s[t] - sum;
    if (base + 8 <= n) {
        int o[8];
#pragma unroll
        for (int j = 0; j < 8; j++) { o[j] = run; run += v[j]; }
        *(int4*)&rp[base]     = make_int4(o[0], o[1], o[2], o[3]);
        *(int4*)&rp[base + 4] = make_int4(o[4], o[5], o[6], o[7]);
    } else {
#pragma unroll
        for (int j = 0; j < 8; j++) { int i = base + j; if (i < n) rp[i] = run; run += v[j]; }
    }
}

// user side now also records user id + edge id per slot (for user-ordered edge pass)
__global__ void fill_kernel(const int* __restrict__ ei, const int* __restrict__ rpu,
                            const int* __restrict__ rpm, int* cu, int* cm,
                            int* __restrict__ eu, int* __restrict__ em,
                            int* __restrict__ us, int* __restrict__ ue, int n) {
    int e = blockIdx.x * blockDim.x + threadIdx.x;
    if (e >= n) return;
    int s = ei[e], d = ei[NE + e];
    int slot = rpu[s] + atomicAdd(&cu[s], 1);
    eu[slot] = d;
    us[slot] = s;
    ue[slot] = e;
    em[rpm[d] + atomicAdd(&cm[d], 1)] = s;
}

// ---------------- merged segment-mean (both directions), 1 wave per node, 4-way unroll ----------------
__global__ void __launch_bounds__(256)
agg_both_kernel(const ushort_t* __restrict__ pu, const ushort_t* __restrict__ pm,
                const int* __restrict__ rpu, const int* __restrict__ rpm,
                const int* __restrict__ eu, const int* __restrict__ em,
                ushort_t* __restrict__ qu, ushort_t* __restrict__ qm, int nbM) {
    int bid = blockIdx.x;
    const ushort_t* src; const int* rp; const int* nbl; ushort_t* dst; int node, n;
    if (bid < nbM) {
        node = bid * 4 + (threadIdx.x >> 6); n = NM; src = pu; rp = rpm; nbl = em; dst = qm;
    } else {
        node = (bid - nbM) * 4 + (threadIdx.x >> 6); n = NU; src = pm; rp = rpu; nbl = eu; dst = qu;
    }
    if (node >= n) return;
    int lane = threadIdx.x & 63;
    int beg = rp[node], end = rp[node + 1];
    float a0 = 0.f, a1 = 0.f;
    int j = beg;
    for (; j + 4 <= end; j += 4) {
        int n0 = nbl[j], n1 = nbl[j + 1], n2 = nbl[j + 2], n3 = nbl[j + 3];
        uint_t v0 = *(const uint_t*)&src[(size_t)n0 * H + lane * 2];
        uint_t v1 = *(const uint_t*)&src[(size_t)n1 * H + lane * 2];
        uint_t v2 = *(const uint_t*)&src[(size_t)n2 * H + lane * 2];
        uint_t v3 = *(const uint_t*)&src[(size_t)n3 * H + lane * 2];
        a0 += (__uint_as_float((v0 & 0xffffu) << 16) + __uint_as_float((v1 & 0xffffu) << 16))
            + (__uint_as_float((v2 & 0xffffu) << 16) + __uint_as_float((v3 & 0xffffu) << 16));
        a1 += (__uint_as_float(v0 & 0xffff0000u) + __uint_as_float(v1 & 0xffff0000u))
            + (__uint_as_float(v2 & 0xffff0000u) + __uint_as_float(v3 & 0xffff0000u));
    }
    for (; j < end; j++) {
        uint_t v = *(const uint_t*)&src[(size_t)nbl[j] * H + lane * 2];
        a0 += __uint_as_float((v & 0xffffu) << 16);
        a1 += __uint_as_float(v & 0xffff0000u);
    }
    int deg = end - beg;
    float inv = 1.0f / (float)(deg > 1 ? deg : 1);
    uint_t r = (uint_t)f2bf(a0 * inv) | ((uint_t)f2bf(a1 * inv) << 16);
    *(uint_t*)&dst[(size_t)node * H + lane * 2] = r;
}

// ---------------- weight converters ----------------
__global__ void convert_w_kernel(const float* __restrict__ c1w, ushort_t* __restrict__ outT) {
    int i = blockIdx.x * 256 + threadIdx.x;
    if (i >= 384 * 128) return;
    int k = i >> 7, n = i & 127;
    outT[n * 384 + k] = f2bf(c1w[i]);
}

__global__ void convert_conv_w_kernel(const float* __restrict__ wl, const float* __restrict__ wr,
                                      ushort_t* __restrict__ outT) {
    int i = blockIdx.x * 256 + threadIdx.x;
    if (i >= 128 * 256) return;
    int col = i >> 8, k = i & 255;
    float v = (k < 128) ? wl[k * H + col] : wr[(k - 128) * H + col];
    outT[i] = f2bf(v);
}

// ---------------- SAGE conv via MFMA, both directions, 8 waves x 16 cols ----------------
__global__ void __launch_bounds__(512)
conv_pair_kernel(const ushort_t* __restrict__ aggM, const ushort_t* __restrict__ selfM,
                 const ushort_t* __restrict__ wTm, const float* __restrict__ blm,
                 ushort_t* __restrict__ outM,
                 const ushort_t* __restrict__ aggU, const ushort_t* __restrict__ selfU,
                 const ushort_t* __restrict__ wTu, const float* __restrict__ blu,
                 ushort_t* __restrict__ outU, int ntM) {
    const ushort_t *agg, *self, *wT; const float* bl; ushort_t* out; int n, tile;
    if ((int)blockIdx.x < ntM) {
        tile = blockIdx.x; agg = aggM; self = selfM; wT = wTm; bl = blm; out = outM; n = NM;
    } else {
        tile = blockIdx.x - ntM; agg = aggU; self = selfU; wT = wTu; bl = blu; out = outU; n = NU;
    }
    int node0 = tile * 64;
    int t = threadIdx.x, lane = t & 63, w = t >> 6;   // w in 0..7
    int l15 = lane & 15, koff = lane >> 4;
    __shared__ ushort_t As[64 * 256];   // 32 KB
    char* Ab = (char*)As;

#pragma unroll
    for (int it = 0; it < 4; it++) {
        int row = it * 16 + w * 2 + (lane >> 5);
        int node = node0 + row; if (node >= n) node = n - 1;
        int g = (lane & 31) ^ (row & 7);
        const ushort_t* src = (g < 16) ? &agg[(size_t)node * H + g * 8]
                                       : &self[(size_t)node * H + (g - 16) * 8];
        gload16(src, Ab + it * 8192 + w * 1024);
    }

    bf16x8 bw[8];
    int col = w * 16 + l15;
#pragma unroll
    for (int ks = 0; ks < 8; ks++)
        bw[ks] = *reinterpret_cast<const bf16x8*>(&wT[col * 256 + ks * 32 + koff * 8]);
    float bias0 = bl[col];
    int sw = l15 & 7;
    __syncthreads();   // drains gload vmcnt

    f32x4 acc[4];
#pragma unroll
    for (int rg = 0; rg < 4; rg++) acc[rg] = (f32x4){bias0, bias0, bias0, bias0};
#pragma unroll
    for (int ks = 0; ks < 8; ks++) {
#pragma unroll
        for (int rg = 0; rg < 4; rg++) {
            int row = rg * 16 + l15;
            const bf16x8 a = *reinterpret_cast<const bf16x8*>(
                Ab + row * 512 + (((ks * 4 + koff) ^ sw) << 4));
            acc[rg] = __builtin_amdgcn_mfma_f32_16x16x32_bf16(a, bw[ks], acc[rg], 0, 0, 0);
        }
    }

#pragma unroll
    for (int rg = 0; rg < 4; rg++)
#pragma unroll
        for (int reg = 0; reg < 4; reg++) {
            int node = node0 + rg * 16 + koff * 4 + reg;
            if (node < n)
                out[(size_t)node * H + col] = f2bf(fmaxf(acc[rg][reg], 0.f));
        }
}

// ---------------- edge MLP via MFMA (user-CSR order, 8 waves x 16 cols, async staging) ----------------
// Slot j in user-CSR order: user us[j] (quasi-sequential), merchant eu[j], edge id ue[j].
__global__ void __launch_bounds__(512)
edge_mlp_mfma_kernel(const ushort_t* __restrict__ h_u, const ushort_t* __restrict__ h_m,
                     const float* __restrict__ ea, const float* __restrict__ ew,
                     const float* __restrict__ ebias,
                     const ushort_t* __restrict__ c1wT, const float* __restrict__ c1b,
                     const float* __restrict__ c2w, const float* __restrict__ c2b,
                     const int* __restrict__ us, const int* __restrict__ eu,
                     const int* __restrict__ ue, float* __restrict__ out) {
    const int ET = 64;
    // bijective XCD-chunked swizzle (m204): consecutive tiles stay on one XCD
    int nwg = gridDim.x;
    int q = nwg >> 3, r = nwg & 7;
    int xcd = blockIdx.x & 7, pos = blockIdx.x >> 3;
    int tile = (xcd < r ? xcd * (q + 1) : r * (q + 1) + (xcd - r) * q) + pos;
    int e0 = tile * ET;

    int t = threadIdx.x;
    int lane = t & 63, w = t >> 6;   // w in 0..7
    int l15 = lane & 15, koff = lane >> 4;

    __shared__ ushort_t As1[ET * 256];  // 32 KB: k 0..255 (hu|hm)
    __shared__ ushort_t As2[ET * 128];  // 16 KB: k 256..383 (edge feats)
    __shared__ float part[8 * ET];      // 2 KB
    __shared__ int se[ET], de[ET], ee[ET];
    char* Ab1 = (char*)As1;
    char* Ab2 = (char*)As2;

    if (t < ET) {
        se[t] = us[e0 + t];
        de[t] = eu[e0 + t];
        ee[t] = ue[e0 + t];
    }
    __syncthreads();   // se/de/ee visible before gather addressing

    // ---- async gather: 4 rounds x 512 threads = 2048 granules (linear dest, source-swizzled) ----
#pragma unroll
    for (int it = 0; it < 4; it++) {
        int row = it * 16 + w * 2 + (lane >> 5);
        int g = (lane & 31) ^ (row & 7);
        const ushort_t* src = (g < 16) ? &h_u[(size_t)se[row] * H + g * 8]
                                       : &h_m[(size_t)de[row] * H + (g - 16) * 8];
        gload16(src, Ab1 + it * 8192 + w * 1024);
    }

    // ---- B slice: wave w owns cols [16w, 16w+16) (overlaps async gather) ----
    bf16x8 bf_[12];
    int col = w * 16 + l15;
#pragma unroll
    for (int ks = 0; ks < 12; ks++)
        bf_[ks] = *reinterpret_cast<const bf16x8*>(&c1wT[col * 384 + ks * 32 + koff * 8]);

    // ---- edge-feature granules on VALU (overlaps async gather) ----
#pragma unroll
    for (int it = 0; it < 2; it++) {
        int lin = it * 512 + t;          // 0..1023 = 64 rows x 16 granules
        int row = lin >> 4, g2 = lin & 15;
        int c = g2 * 8;
        int eid = ee[row];
        float a0 = ea[(size_t)eid * 2], a1 = ea[(size_t)eid * 2 + 1];
        float4 w0a = *(const float4*)&ew[c];
        float4 w0b = *(const float4*)&ew[c + 4];
        float4 w1a = *(const float4*)&ew[H + c];
        float4 w1b = *(const float4*)&ew[H + c + 4];
        float4 bba = *(const float4*)&ebias[c];
        float4 bbb = *(const float4*)&ebias[c + 4];
        float v[8];
        v[0] = fmaxf(fmaf(a0, w0a.x, fmaf(a1, w1a.x, bba.x)), 0.f);
        v[1] = fmaxf(fmaf(a0, w0a.y, fmaf(a1, w1a.y, bba.y)), 0.f);
        v[2] = fmaxf(fmaf(a0, w0a.z, fmaf(a1, w1a.z, bba.z)), 0.f);
        v[3] = fmaxf(fmaf(a0, w0a.w, fmaf(a1, w1a.w, bba.w)), 0.f);
        v[4] = fmaxf(fmaf(a0, w0b.x, fmaf(a1, w1b.x, bbb.x)), 0.f);
        v[5] = fmaxf(fmaf(a0, w0b.y, fmaf(a1, w1b.y, bbb.y)), 0.f);
        v[6] = fmaxf(fmaf(a0, w0b.z, fmaf(a1, w1b.z, bbb.z)), 0.f);
        v[7] = fmaxf(fmaf(a0, w0b.w, fmaf(a1, w1b.w, bbb.w)), 0.f);
        union { ushort_t u[8]; uint4 q; } pk;
#pragma unroll
        for (int j = 0; j < 8; j++) pk.u[j] = f2bf(v[j]);
        *(uint4*)(Ab2 + row * 256 + ((g2 ^ (row & 7)) << 4)) = pk.q;
    }
    __syncthreads();   // drains gload vmcnt + LDS writes

    int sw = l15 & 7;
    float bias0 = c1b[col];
    f32x4 acc[4];
#pragma unroll
    for (int rg = 0; rg < 4; rg++) acc[rg] = (f32x4){bias0, bias0, bias0, bias0};
#pragma unroll
    for (int ks = 0; ks < 12; ks++) {
#pragma unroll
        for (int rg = 0; rg < 4; rg++) {
            int row = rg * 16 + l15;
            const bf16x8 a = (ks < 8)
                ? *reinterpret_cast<const bf16x8*>(Ab1 + row * 512 + (((ks * 4 + koff) ^ sw) << 4))
                : *reinterpret_cast<const bf16x8*>(Ab2 + row * 256 + ((((ks - 8) * 4 + koff) ^ sw) << 4));
            acc[rg] = __builtin_amdgcn_mfma_f32_16x16x32_bf16(a, bf_[ks], acc[rg], 0, 0, 0);
        }
    }

    float c2v = c2w[col];
#pragma unroll
    for (int rg = 0; rg < 4; rg++) {
#pragma unroll
        for (int reg = 0; reg < 4; reg++) {
            float p = fmaxf(acc[rg][reg], 0.f) * c2v;
#pragma unroll
            for (int off = 8; off >= 1; off >>= 1) p += __shfl_xor(p, off, 64);
            if (l15 == 0) part[w * ET + rg * 16 + koff * 4 + reg] = p;
        }
    }
    __syncthreads();
    if (t < ET) {
        float s = part[t];
#pragma unroll
        for (int ww = 1; ww < 8; ww++) s += part[ww * ET + t];
        out[ee[t]] = s + c2b[0];   // scattered 4B write (edge-id order)
    }
}

extern "C" void kernel_launch(void* const* d_in, const int* in_sizes, int n_in,
                              void* d_out, int out_size, void* d_ws, size_t ws_size,
                              hipStream_t stream) {
    const float* user_x     = (const float*)d_in[0];
    const float* merchant_x = (const float*)d_in[1];
    const float* edge_attr  = (const float*)d_in[2];
    const float* user_w     = (const float*)d_in[3];
    const float* user_b     = (const float*)d_in[4];
    const float* merch_w    = (const float*)d_in[5];
    const float* merch_b    = (const float*)d_in[6];
    const float* edge_w     = (const float*)d_in[7];
    const float* edge_b     = (const float*)d_in[8];
    const float* u2m_wl     = (const float*)d_in[9];
    const float* u2m_bl     = (const float*)d_in[10];
    const float* u2m_wr     = (const float*)d_in[11];
    const float* m2u_wl     = (const float*)d_in[12];
    const float* m2u_bl     = (const float*)d_in[13];
    const float* m2u_wr     = (const float*)d_in[14];
    const float* c1w        = (const float*)d_in[15];
    const float* c1b        = (const float*)d_in[16];
    const float* c2w        = (const float*)d_in[17];
    const float* c2b        = (const float*)d_in[18];
    const int*   ei         = (const int*)d_in[19];
    float* out = (float*)d_out;

    ushort_t* hu   = (ushort_t*)d_ws;
    ushort_t* hm   = hu  + (size_t)NU * H;
    ushort_t* hu2  = hm  + (size_t)NM * H;
    ushort_t* hm2  = hu2 + (size_t)NU * H;
    ushort_t* c1wT = hm2 + (size_t)NM * H;
    ushort_t* wTc  = c1wT + 384 * 128;
    int* rpu = (int*)(wTc + 4 * 128 * 256);
    int* rpm = rpu + (NU + 1);
    int* cu  = rpm + (NM + 1);
    int* cm  = cu + NU;
    int* eu  = cm + NM;
    int* em  = eu + NE;
    int* us  = em + NE;
    int* ue  = us + NE;
    int* bsum_u = ue + NE;
    int* boff_u = bsum_u + 128;
    int* bsum_m = boff_u + 128;
    int* boff_m = bsum_m + 128;

    const int NBU = (NU + 2047) / 2048;
    const int NBM = (NM + 2047) / 2048;

    hipMemsetAsync(cu, 0, (size_t)(NU + NM) * sizeof(int), stream);

    encode_bf16_kernel<<<(NU * 16 + 255) / 256, 256, 0, stream>>>(user_x, user_w, user_b, hu, NU, 3);
    encode_bf16_kernel<<<(NM * 16 + 255) / 256, 256, 0, stream>>>(merchant_x, merch_w, merch_b, hm, NM, 2);
    convert_w_kernel<<<(384 * 128 + 255) / 256, 256, 0, stream>>>(c1w, c1wT);
    for (int l = 0; l < 2; l++) {
        convert_conv_w_kernel<<<128, 256, 0, stream>>>(
            u2m_wl + (size_t)l * H * H, u2m_wr + (size_t)l * H * H, wTc + (size_t)l * 128 * 256);
        convert_conv_w_kernel<<<128, 256, 0, stream>>>(
            m2u_wl + (size_t)l * H * H, m2u_wr + (size_t)l * H * H, wTc + (size_t)(2 + l) * 128 * 256);
    }

    count_kernel<<<(NE + 255) / 256, 256, 0, stream>>>(ei, cu, cm, NE);
    scanA_kernel<<<NBU, 256, 0, stream>>>(cu, bsum_u, NU);
    scanB_kernel<<<1, 256, 0, stream>>>(bsum_u, boff_u, NBU, rpu + NU);
    scanC_kernel<<<NBU, 256, 0, stream>>>(cu, boff_u, rpu, NU);
    scanA_kernel<<<NBM, 256, 0, stream>>>(cm, bsum_m, NM);
    scanB_kernel<<<1, 256, 0, stream>>>(bsum_m, boff_m, NBM, rpm + NM);
    scanC_kernel<<<NBM, 256, 0, stream>>>(cm, boff_m, rpm, NM);
    hipMemsetAsync(cu, 0, (size_t)(NU + NM) * sizeof(int), stream);
    fill_kernel<<<(NE + 255) / 256, 256, 0, stream>>>(ei, rpu, rpm, cu, cm, eu, em, us, ue, NE);

    const int AGG_NBM = (NM + 3) / 4;          // 12500
    const int AGG_NBU = (NU + 3) / 4;          // 50000
    const int CONV_TILES_M = (NM + 63) / 64;   // 782
    const int CONV_TILES_U = (NU + 63) / 64;   // 3125

    const ushort_t* pu = hu; const ushort_t* pm = hm;
    ushort_t* qu = hu2; ushort_t* qm = hm2;
    for (int l = 0; l < 2; l++) {
        agg_both_kernel<<<AGG_NBM + AGG_NBU, 256, 0, stream>>>(
            pu, pm, rpu, rpm, eu, em, qu, qm, AGG_NBM);
        conv_pair_kernel<<<CONV_TILES_M + CONV_TILES_U, 512, 0, stream>>>(
            qm, pm, wTc + (size_t)l * 128 * 256, u2m_bl + (size_t)l * H, qm,
            qu, pu, wTc + (size_t)(2 + l) * 128 * 256, m2u_bl + (size_t)l * H, qu,
            CONV_TILES_M);
        const ushort_t* tu = pu; pu = qu; qu = (ushort_t*)tu;
        const ushort_t* tm = pm; pm = qm; qm = (ushort_t*)tm;
    }

    edge_mlp_mfma_kernel<<<NE / 64, 512, 0, stream>>>(pu, pm, edge_attr, edge_w, edge_b,
                                                      c1wT, c1b, c2w, c2b, us, eu, ue, out);
}

// Round 11
// 580.125 us; speedup vs baseline: 1.9785x; 1.0847x over previous
//
#include <hip/hip_runtime.h>

#define H   128
#define NU  200000
#define NM  50000
#define NE  600000

typedef __attribute__((ext_vector_type(8))) short bf16x8;
typedef __attribute__((ext_vector_type(4))) float f32x4;
typedef unsigned short ushort_t;
typedef unsigned int uint_t;

__device__ __forceinline__ ushort_t f2bf(float x) {
    uint_t b = __float_as_uint(x);
    return (ushort_t)((b + 0x7FFF + ((b >> 16) & 1)) >> 16);  // RNE
}

// async 16B global->LDS. lds base must be wave-uniform; HW scatters lane l -> base + l*16.
__device__ __forceinline__ void gload16(const void* gsrc, void* lds_base) {
    __builtin_amdgcn_global_load_lds(
        (const __attribute__((address_space(1))) unsigned int*)gsrc,
        (__attribute__((address_space(3))) unsigned int*)lds_base,
        16, 0, 0);
}

// ---------------- encoders: h = bf16(relu(x @ W + b)), K small ----------------
__global__ void __launch_bounds__(256)
encode_bf16_kernel(const float* __restrict__ x, const float* __restrict__ W,
                   const float* __restrict__ b, ushort_t* __restrict__ h,
                   int n, int K) {
    int idx = blockIdx.x * 256 + threadIdx.x;
    if (idx >= n * 16) return;
    int r = idx >> 4, c0 = (idx & 15) * 8;
    float4 ba = *(const float4*)&b[c0], bb = *(const float4*)&b[c0 + 4];
    float acc[8] = {ba.x, ba.y, ba.z, ba.w, bb.x, bb.y, bb.z, bb.w};
    for (int k = 0; k < K; k++) {
        float xv = x[r * K + k];
        float4 wa = *(const float4*)&W[k * H + c0], wb = *(const float4*)&W[k * H + c0 + 4];
        acc[0] = fmaf(xv, wa.x, acc[0]); acc[1] = fmaf(xv, wa.y, acc[1]);
        acc[2] = fmaf(xv, wa.z, acc[2]); acc[3] = fmaf(xv, wa.w, acc[3]);
        acc[4] = fmaf(xv, wb.x, acc[4]); acc[5] = fmaf(xv, wb.y, acc[5]);
        acc[6] = fmaf(xv, wb.z, acc[6]); acc[7] = fmaf(xv, wb.w, acc[7]);
    }
    union { ushort_t u[8]; uint4 q; } pk;
#pragma unroll
    for (int j = 0; j < 8; j++) pk.u[j] = f2bf(fmaxf(acc[j], 0.f));
    *(uint4*)&h[(size_t)r * H + c0] = pk.q;
}

// ---------------- CSR build ----------------
__global__ void count_kernel(const int* __restrict__ ei, int* cu, int* cm, int n) {
    int e = blockIdx.x * blockDim.x + threadIdx.x;
    if (e >= n) return;
    atomicAdd(&cu[ei[e]], 1);
    atomicAdd(&cm[ei[NE + e]], 1);
}

__global__ void __launch_bounds__(256)
scanA_kernel(const int* __restrict__ cnt, int* __restrict__ bsum, int n) {
    __shared__ int s[256];
    int b = blockIdx.x, t = threadIdx.x;
    int base = b * 2048 + t * 8;
    int sum = 0;
    if (base + 8 <= n) {
        int4 a = *(const int4*)&cnt[base];
        int4 c = *(const int4*)&cnt[base + 4];
        sum = a.x + a.y + a.z + a.w + c.x + c.y + c.z + c.w;
    } else {
        for (int j = 0; j < 8; j++) { int i = base + j; if (i < n) sum += cnt[i]; }
    }
    s[t] = sum;
    __syncthreads();
    for (int off = 128; off >= 1; off >>= 1) {
        if (t < off) s[t] += s[t + off];
        __syncthreads();
    }
    if (t == 0) bsum[b] = s[0];
}

__global__ void __launch_bounds__(256)
scanB_kernel(const int* __restrict__ bsum, int* __restrict__ boff, int nb,
             int* __restrict__ rp_total) {
    __shared__ int s[256];
    int t = threadIdx.x;
    int v = (t < nb) ? bsum[t] : 0;
    s[t] = v;
    __syncthreads();
    for (int off = 1; off < 256; off <<= 1) {
        int x = (t >= off) ? s[t - off] : 0;
        __syncthreads();
        s[t] += x;
        __syncthreads();
    }
    if (t < nb) boff[t] = s[t] - v;
    if (t == 255) rp_total[0] = s[255];
}

__global__ void __launch_bounds__(256)
scanC_kernel(const int* __restrict__ cnt, const int* __restrict__ boff,
             int* __restrict__ rp, int n) {
    __shared__ int s[256];
    int b = blockIdx.x, t = threadIdx.x;
    int base = b * 2048 + t * 8;
    int v[8];
    int sum = 0;
    if (base + 8 <= n) {
        int4 a = *(const int4*)&cnt[base];
        int4 c = *(const int4*)&cnt[base + 4];
        v[0] = a.x; v[1] = a.y; v[2] = a.z; v[3] = a.w;
        v[4] = c.x; v[5] = c.y; v[6] = c.z; v[7] = c.w;
#pragma unroll
        for (int j = 0; j < 8; j++) sum += v[j];
    } else {
#pragma unroll
        for (int j = 0; j < 8; j++) { int i = base + j; v[j] = (i < n) ? cnt[i] : 0; sum += v[j]; }
    }
    s[t] = sum;
    __syncthreads();
    for (int off = 1; off < 256; off <<= 1) {
        int x = (t >= off) ? s[t - off] : 0;
        __syncthreads();
        s[t] += x;
        __syncthreads();
    }
    int run = boff[b] + s[t] - sum;
    if (base + 8 <= n) {
        int o[8];
#pragma unroll
        for (int j = 0; j < 8; j++) { o[j] = run; run += v[j]; }
        *(int4*)&rp[base]     = make_int4(o[0], o[1], o[2], o[3]);
        *(int4*)&rp[base + 4] = make_int4(o[4], o[5], o[6], o[7]);
    } else {
#pragma unroll
        for (int j = 0; j < 8; j++) { int i = base + j; if (i < n) rp[i] = run; run += v[j]; }
    }
}

// user side records user id + edge id per slot (for user-ordered edge pass)
__global__ void fill_kernel(const int* __restrict__ ei, const int* __restrict__ rpu,
                            const int* __restrict__ rpm, int* cu, int* cm,
                            int* __restrict__ eu, int* __restrict__ em,
                            int* __restrict__ us, int* __restrict__ ue, int n) {
    int e = blockIdx.x * blockDim.x + threadIdx.x;
    if (e >= n) return;
    int s = ei[e], d = ei[NE + e];
    int slot = rpu[s] + atomicAdd(&cu[s], 1);
    eu[slot] = d;
    us[slot] = s;
    ue[slot] = e;
    em[rpm[d] + atomicAdd(&cm[d], 1)] = s;
}

// ---------------- weight converters ----------------
__global__ void convert_w_kernel(const float* __restrict__ c1w, ushort_t* __restrict__ outT) {
    int i = blockIdx.x * 256 + threadIdx.x;
    if (i >= 384 * 128) return;
    int k = i >> 7, n = i & 127;
    outT[n * 384 + k] = f2bf(c1w[i]);
}

__global__ void convert_conv_w_kernel(const float* __restrict__ wl, const float* __restrict__ wr,
                                      ushort_t* __restrict__ outT) {
    int i = blockIdx.x * 256 + threadIdx.x;
    if (i >= 128 * 256) return;
    int col = i >> 8, k = i & 255;
    float v = (k < 128) ? wl[k * H + col] : wr[(k - 128) * H + col];
    outT[i] = f2bf(v);
}

// ---------------- FUSED SAGE conv: gather+mean+MFMA, both directions ----------------
// out = bf16(relu([mean_nb | self] @ wT' + bl)). 64 nodes/tile, 512 threads (8 waves).
// Phase 0: async gload16 self rows -> AsSelf (linear dest, source-swizzled).
// Phase 1: wave w gathers+means nodes w*8..w*8+7 (4-way unrolled) -> AsAgg (swizzled VALU writes).
// Phase 2: B slice -> regs, barrier, 8xK MFMA (ks<4 from AsAgg, ks>=4 from AsSelf), store.
__global__ void __launch_bounds__(512)
conv_pair_kernel(const ushort_t* __restrict__ hu_in, const ushort_t* __restrict__ hm_in,
                 const int* __restrict__ rpu, const int* __restrict__ rpm,
                 const int* __restrict__ eu, const int* __restrict__ em,
                 const ushort_t* __restrict__ wTm, const float* __restrict__ blm,
                 ushort_t* __restrict__ outM,
                 const ushort_t* __restrict__ wTu, const float* __restrict__ blu,
                 ushort_t* __restrict__ outU, int ntM) {
    const ushort_t *nbr, *self, *wT; const float* bl; ushort_t* out;
    const int *rp, *nbl; int n, tile;
    if ((int)blockIdx.x < ntM) {
        tile = blockIdx.x; nbr = hu_in; self = hm_in; rp = rpm; nbl = em;
        wT = wTm; bl = blm; out = outM; n = NM;
    } else {
        tile = blockIdx.x - ntM; nbr = hm_in; self = hu_in; rp = rpu; nbl = eu;
        wT = wTu; bl = blu; out = outU; n = NU;
    }
    int node0 = tile * 64;
    int t = threadIdx.x, lane = t & 63, w = t >> 6;   // w in 0..7
    int l15 = lane & 15, koff = lane >> 4;
    __shared__ ushort_t AsAgg[64 * 128];   // 16 KB: rows of 16 granules (256 B)
    __shared__ ushort_t AsSelf[64 * 128];  // 16 KB
    char* Aa = (char*)AsAgg;
    char* Asf = (char*)AsSelf;

    // ---- phase 0: async self staging (2 rounds; wave covers 4 rows = 1 KB per round) ----
#pragma unroll
    for (int it = 0; it < 2; it++) {
        int row = it * 32 + w * 4 + (lane >> 4);
        int node = node0 + row; if (node >= n) node = n - 1;
        int g = (lane & 15) ^ (row & 7);
        gload16(&self[(size_t)node * H + g * 8], Asf + it * 8192 + w * 1024);
    }

    // ---- phase 1: gather + mean, wave w -> rows w*8 .. w*8+7 ----
    for (int i = 0; i < 8; i++) {
        int row = w * 8 + i;
        int node = node0 + row;
        float a0 = 0.f, a1 = 0.f;
        int beg = 0, end = 0;
        if (node < n) { beg = rp[node]; end = rp[node + 1]; }
        int j = beg;
        for (; j + 4 <= end; j += 4) {
            int n0 = nbl[j], n1 = nbl[j + 1], n2 = nbl[j + 2], n3 = nbl[j + 3];
            uint_t v0 = *(const uint_t*)&nbr[(size_t)n0 * H + lane * 2];
            uint_t v1 = *(const uint_t*)&nbr[(size_t)n1 * H + lane * 2];
            uint_t v2 = *(const uint_t*)&nbr[(size_t)n2 * H + lane * 2];
            uint_t v3 = *(const uint_t*)&nbr[(size_t)n3 * H + lane * 2];
            a0 += (__uint_as_float((v0 & 0xffffu) << 16) + __uint_as_float((v1 & 0xffffu) << 16))
                + (__uint_as_float((v2 & 0xffffu) << 16) + __uint_as_float((v3 & 0xffffu) << 16));
            a1 += (__uint_as_float(v0 & 0xffff0000u) + __uint_as_float(v1 & 0xffff0000u))
                + (__uint_as_float(v2 & 0xffff0000u) + __uint_as_float(v3 & 0xffff0000u));
        }
        for (; j < end; j++) {
            uint_t v = *(const uint_t*)&nbr[(size_t)nbl[j] * H + lane * 2];
            a0 += __uint_as_float((v & 0xffffu) << 16);
            a1 += __uint_as_float(v & 0xffff0000u);
        }
        int deg = end - beg;
        float inv = 1.0f / (float)(deg > 1 ? deg : 1);
        uint_t r = (uint_t)f2bf(a0 * inv) | ((uint_t)f2bf(a1 * inv) << 16);
        *(uint_t*)(Aa + row * 256 + ((((lane >> 2)) ^ (row & 7)) << 4) + (lane & 3) * 4) = r;
    }

    // ---- B slice after gather (short live range) ----
    bf16x8 bw[8];
    int col = w * 16 + l15;
#pragma unroll
    for (int ks = 0; ks < 8; ks++)
        bw[ks] = *reinterpret_cast<const bf16x8*>(&wT[col * 256 + ks * 32 + koff * 8]);
    float bias0 = bl[col];
    int sw = l15 & 7;
    __syncthreads();   // drains gload vmcnt + LDS writes

    f32x4 acc[4];
#pragma unroll
    for (int rg = 0; rg < 4; rg++) acc[rg] = (f32x4){bias0, bias0, bias0, bias0};
#pragma unroll
    for (int ks = 0; ks < 8; ks++) {
#pragma unroll
        for (int rg = 0; rg < 4; rg++) {
            int row = rg * 16 + l15;
            const bf16x8 a = (ks < 4)
                ? *reinterpret_cast<const bf16x8*>(Aa  + row * 256 + (((ks * 4 + koff) ^ sw) << 4))
                : *reinterpret_cast<const bf16x8*>(Asf + row * 256 + ((((ks - 4) * 4 + koff) ^ sw) << 4));
            acc[rg] = __builtin_amdgcn_mfma_f32_16x16x32_bf16(a, bw[ks], acc[rg], 0, 0, 0);
        }
    }

#pragma unroll
    for (int rg = 0; rg < 4; rg++)
#pragma unroll
        for (int reg = 0; reg < 4; reg++) {
            int node = node0 + rg * 16 + koff * 4 + reg;
            if (node < n)
                out[(size_t)node * H + col] = f2bf(fmaxf(acc[rg][reg], 0.f));
        }
}

// ---------------- edge MLP via MFMA (user-CSR order, 8 waves x 16 cols, async staging) ----------------
__global__ void __launch_bounds__(512)
edge_mlp_mfma_kernel(const ushort_t* __restrict__ h_u, const ushort_t* __restrict__ h_m,
                     const float* __restrict__ ea, const float* __restrict__ ew,
                     const float* __restrict__ ebias,
                     const ushort_t* __restrict__ c1wT, const float* __restrict__ c1b,
                     const float* __restrict__ c2w, const float* __restrict__ c2b,
                     const int* __restrict__ us, const int* __restrict__ eu,
                     const int* __restrict__ ue, float* __restrict__ out) {
    const int ET = 64;
    // bijective XCD-chunked swizzle (m204): consecutive tiles stay on one XCD
    int nwg = gridDim.x;
    int q = nwg >> 3, r = nwg & 7;
    int xcd = blockIdx.x & 7, pos = blockIdx.x >> 3;
    int tile = (xcd < r ? xcd * (q + 1) : r * (q + 1) + (xcd - r) * q) + pos;
    int e0 = tile * ET;

    int t = threadIdx.x;
    int lane = t & 63, w = t >> 6;   // w in 0..7
    int l15 = lane & 15, koff = lane >> 4;

    __shared__ ushort_t As1[ET * 256];  // 32 KB: k 0..255 (hu|hm)
    __shared__ ushort_t As2[ET * 128];  // 16 KB: k 256..383 (edge feats)
    __shared__ float part[8 * ET];      // 2 KB
    __shared__ int se[ET], de[ET], ee[ET];
    char* Ab1 = (char*)As1;
    char* Ab2 = (char*)As2;

    if (t < ET) {
        se[t] = us[e0 + t];
        de[t] = eu[e0 + t];
        ee[t] = ue[e0 + t];
    }
    __syncthreads();   // se/de/ee visible before gather addressing

    // ---- async gather: 4 rounds x 512 threads = 2048 granules (linear dest, source-swizzled) ----
#pragma unroll
    for (int it = 0; it < 4; it++) {
        int row = it * 16 + w * 2 + (lane >> 5);
        int g = (lane & 31) ^ (row & 7);
        const ushort_t* src = (g < 16) ? &h_u[(size_t)se[row] * H + g * 8]
                                       : &h_m[(size_t)de[row] * H + (g - 16) * 8];
        gload16(src, Ab1 + it * 8192 + w * 1024);
    }

    // ---- B slice: wave w owns cols [16w, 16w+16) (overlaps async gather) ----
    bf16x8 bf_[12];
    int col = w * 16 + l15;
#pragma unroll
    for (int ks = 0; ks < 12; ks++)
        bf_[ks] = *reinterpret_cast<const bf16x8*>(&c1wT[col * 384 + ks * 32 + koff * 8]);

    // ---- edge-feature granules on VALU (overlaps async gather) ----
#pragma unroll
    for (int it = 0; it < 2; it++) {
        int lin = it * 512 + t;          // 0..1023 = 64 rows x 16 granules
        int row = lin >> 4, g2 = lin & 15;
        int c = g2 * 8;
        int eid = ee[row];
        float a0 = ea[(size_t)eid * 2], a1 = ea[(size_t)eid * 2 + 1];
        float4 w0a = *(const float4*)&ew[c];
        float4 w0b = *(const float4*)&ew[c + 4];
        float4 w1a = *(const float4*)&ew[H + c];
        float4 w1b = *(const float4*)&ew[H + c + 4];
        float4 bba = *(const float4*)&ebias[c];
        float4 bbb = *(const float4*)&ebias[c + 4];
        float v[8];
        v[0] = fmaxf(fmaf(a0, w0a.x, fmaf(a1, w1a.x, bba.x)), 0.f);
        v[1] = fmaxf(fmaf(a0, w0a.y, fmaf(a1, w1a.y, bba.y)), 0.f);
        v[2] = fmaxf(fmaf(a0, w0a.z, fmaf(a1, w1a.z, bba.z)), 0.f);
        v[3] = fmaxf(fmaf(a0, w0a.w, fmaf(a1, w1a.w, bba.w)), 0.f);
        v[4] = fmaxf(fmaf(a0, w0b.x, fmaf(a1, w1b.x, bbb.x)), 0.f);
        v[5] = fmaxf(fmaf(a0, w0b.y, fmaf(a1, w1b.y, bbb.y)), 0.f);
        v[6] = fmaxf(fmaf(a0, w0b.z, fmaf(a1, w1b.z, bbb.z)), 0.f);
        v[7] = fmaxf(fmaf(a0, w0b.w, fmaf(a1, w1b.w, bbb.w)), 0.f);
        union { ushort_t u[8]; uint4 q; } pk;
#pragma unroll
        for (int j = 0; j < 8; j++) pk.u[j] = f2bf(v[j]);
        *(uint4*)(Ab2 + row * 256 + ((g2 ^ (row & 7)) << 4)) = pk.q;
    }
    __syncthreads();   // drains gload vmcnt + LDS writes

    int sw = l15 & 7;
    float bias0 = c1b[col];
    f32x4 acc[4];
#pragma unroll
    for (int rg = 0; rg < 4; rg++) acc[rg] = (f32x4){bias0, bias0, bias0, bias0};
#pragma unroll
    for (int ks = 0; ks < 12; ks++) {
#pragma unroll
        for (int rg = 0; rg < 4; rg++) {
            int row = rg * 16 + l15;
            const bf16x8 a = (ks < 8)
                ? *reinterpret_cast<const bf16x8*>(Ab1 + row * 512 + (((ks * 4 + koff) ^ sw) << 4))
                : *reinterpret_cast<const bf16x8*>(Ab2 + row * 256 + ((((ks - 8) * 4 + koff) ^ sw) << 4));
            acc[rg] = __builtin_amdgcn_mfma_f32_16x16x32_bf16(a, bf_[ks], acc[rg], 0, 0, 0);
        }
    }

    float c2v = c2w[col];
#pragma unroll
    for (int rg = 0; rg < 4; rg++) {
#pragma unroll
        for (int reg = 0; reg < 4; reg++) {
            float p = fmaxf(acc[rg][reg], 0.f) * c2v;
#pragma unroll
            for (int off = 8; off >= 1; off >>= 1) p += __shfl_xor(p, off, 64);
            if (l15 == 0) part[w * ET + rg * 16 + koff * 4 + reg] = p;
        }
    }
    __syncthreads();
    if (t < ET) {
        float s = part[t];
#pragma unroll
        for (int ww = 1; ww < 8; ww++) s += part[ww * ET + t];
        out[ee[t]] = s + c2b[0];   // scattered 4B write (edge-id order)
    }
}

extern "C" void kernel_launch(void* const* d_in, const int* in_sizes, int n_in,
                              void* d_out, int out_size, void* d_ws, size_t ws_size,
                              hipStream_t stream) {
    const float* user_x     = (const float*)d_in[0];
    const float* merchant_x = (const float*)d_in[1];
    const float* edge_attr  = (const float*)d_in[2];
    const float* user_w     = (const float*)d_in[3];
    const float* user_b     = (const float*)d_in[4];
    const float* merch_w    = (const float*)d_in[5];
    const float* merch_b    = (const float*)d_in[6];
    const float* edge_w     = (const float*)d_in[7];
    const float* edge_b     = (const float*)d_in[8];
    const float* u2m_wl     = (const float*)d_in[9];
    const float* u2m_bl     = (const float*)d_in[10];
    const float* u2m_wr     = (const float*)d_in[11];
    const float* m2u_wl     = (const float*)d_in[12];
    const float* m2u_bl     = (const float*)d_in[13];
    const float* m2u_wr     = (const float*)d_in[14];
    const float* c1w        = (const float*)d_in[15];
    const float* c1b        = (const float*)d_in[16];
    const float* c2w        = (const float*)d_in[17];
    const float* c2b        = (const float*)d_in[18];
    const int*   ei         = (const int*)d_in[19];
    float* out = (float*)d_out;

    ushort_t* hu   = (ushort_t*)d_ws;
    ushort_t* hm   = hu  + (size_t)NU * H;
    ushort_t* hu2  = hm  + (size_t)NM * H;
    ushort_t* hm2  = hu2 + (size_t)NU * H;
    ushort_t* c1wT = hm2 + (size_t)NM * H;
    ushort_t* wTc  = c1wT + 384 * 128;
    int* rpu = (int*)(wTc + 4 * 128 * 256);
    int* rpm = rpu + (NU + 1);
    int* cu  = rpm + (NM + 1);
    int* cm  = cu + NU;
    int* eu  = cm + NM;
    int* em  = eu + NE;
    int* us  = em + NE;
    int* ue  = us + NE;
    int* bsum_u = ue + NE;
    int* boff_u = bsum_u + 128;
    int* bsum_m = boff_u + 128;
    int* boff_m = bsum_m + 128;

    const int NBU = (NU + 2047) / 2048;
    const int NBM = (NM + 2047) / 2048;

    hipMemsetAsync(cu, 0, (size_t)(NU + NM) * sizeof(int), stream);

    encode_bf16_kernel<<<(NU * 16 + 255) / 256, 256, 0, stream>>>(user_x, user_w, user_b, hu, NU, 3);
    encode_bf16_kernel<<<(NM * 16 + 255) / 256, 256, 0, stream>>>(merchant_x, merch_w, merch_b, hm, NM, 2);
    convert_w_kernel<<<(384 * 128 + 255) / 256, 256, 0, stream>>>(c1w, c1wT);
    for (int l = 0; l < 2; l++) {
        convert_conv_w_kernel<<<128, 256, 0, stream>>>(
            u2m_wl + (size_t)l * H * H, u2m_wr + (size_t)l * H * H, wTc + (size_t)l * 128 * 256);
        convert_conv_w_kernel<<<128, 256, 0, stream>>>(
            m2u_wl + (size_t)l * H * H, m2u_wr + (size_t)l * H * H, wTc + (size_t)(2 + l) * 128 * 256);
    }

    count_kernel<<<(NE + 255) / 256, 256, 0, stream>>>(ei, cu, cm, NE);
    scanA_kernel<<<NBU, 256, 0, stream>>>(cu, bsum_u, NU);
    scanB_kernel<<<1, 256, 0, stream>>>(bsum_u, boff_u, NBU, rpu + NU);
    scanC_kernel<<<NBU, 256, 0, stream>>>(cu, boff_u, rpu, NU);
    scanA_kernel<<<NBM, 256, 0, stream>>>(cm, bsum_m, NM);
    scanB_kernel<<<1, 256, 0, stream>>>(bsum_m, boff_m, NBM, rpm + NM);
    scanC_kernel<<<NBM, 256, 0, stream>>>(cm, boff_m, rpm, NM);
    hipMemsetAsync(cu, 0, (size_t)(NU + NM) * sizeof(int), stream);
    fill_kernel<<<(NE + 255) / 256, 256, 0, stream>>>(ei, rpu, rpm, cu, cm, eu, em, us, ue, NE);

    const int CONV_TILES_M = (NM + 63) / 64;   // 782
    const int CONV_TILES_U = (NU + 63) / 64;   // 3125

    const ushort_t* pu = hu; const ushort_t* pm = hm;
    ushort_t* qu = hu2; ushort_t* qm = hm2;
    for (int l = 0; l < 2; l++) {
        conv_pair_kernel<<<CONV_TILES_M + CONV_TILES_U, 512, 0, stream>>>(
            pu, pm, rpu, rpm, eu, em,
            wTc + (size_t)l * 128 * 256, u2m_bl + (size_t)l * H, qm,
            wTc + (size_t)(2 + l) * 128 * 256, m2u_bl + (size_t)l * H, qu,
            CONV_TILES_M);
        const ushort_t* tu = pu; pu = qu; qu = (ushort_t*)tu;
        const ushort_t* tm = pm; pm = qm; qm = (ushort_t*)tm;
    }

    edge_mlp_mfma_kernel<<<NE / 64, 512, 0, stream>>>(pu, pm, edge_attr, edge_w, edge_b,
                                                      c1wT, c1b, c2w, c2b, us, eu, ue, out);
}

// Round 12
// 522.764 us; speedup vs baseline: 2.1956x; 1.1097x over previous
//
#include <hip/hip_runtime.h>

#define H   128
#define NU  200000
#define NM  50000
#define NE  600000

typedef __attribute__((ext_vector_type(8))) short bf16x8;
typedef __attribute__((ext_vector_type(4))) float f32x4;
typedef unsigned short ushort_t;
typedef unsigned int uint_t;

__device__ __forceinline__ ushort_t f2bf(float x) {
    uint_t b = __float_as_uint(x);
    return (ushort_t)((b + 0x7FFF + ((b >> 16) & 1)) >> 16);  // RNE
}

// async 16B global->LDS. lds base must be wave-uniform; HW scatters lane l -> base + l*16.
__device__ __forceinline__ void gload16(const void* gsrc, void* lds_base) {
    __builtin_amdgcn_global_load_lds(
        (const __attribute__((address_space(1))) unsigned int*)gsrc,
        (__attribute__((address_space(3))) unsigned int*)lds_base,
        16, 0, 0);
}

// ---------------- encoders: h = bf16(relu(x @ W + b)), K small ----------------
__global__ void __launch_bounds__(256)
encode_bf16_kernel(const float* __restrict__ x, const float* __restrict__ W,
                   const float* __restrict__ b, ushort_t* __restrict__ h,
                   int n, int K) {
    int idx = blockIdx.x * 256 + threadIdx.x;
    if (idx >= n * 16) return;
    int r = idx >> 4, c0 = (idx & 15) * 8;
    float4 ba = *(const float4*)&b[c0], bb = *(const float4*)&b[c0 + 4];
    float acc[8] = {ba.x, ba.y, ba.z, ba.w, bb.x, bb.y, bb.z, bb.w};
    for (int k = 0; k < K; k++) {
        float xv = x[r * K + k];
        float4 wa = *(const float4*)&W[k * H + c0], wb = *(const float4*)&W[k * H + c0 + 4];
        acc[0] = fmaf(xv, wa.x, acc[0]); acc[1] = fmaf(xv, wa.y, acc[1]);
        acc[2] = fmaf(xv, wa.z, acc[2]); acc[3] = fmaf(xv, wa.w, acc[3]);
        acc[4] = fmaf(xv, wb.x, acc[4]); acc[5] = fmaf(xv, wb.y, acc[5]);
        acc[6] = fmaf(xv, wb.z, acc[6]); acc[7] = fmaf(xv, wb.w, acc[7]);
    }
    union { ushort_t u[8]; uint4 q; } pk;
#pragma unroll
    for (int j = 0; j < 8; j++) pk.u[j] = f2bf(fmaxf(acc[j], 0.f));
    *(uint4*)&h[(size_t)r * H + c0] = pk.q;
}

// ---------------- CSR build ----------------
__global__ void count_kernel(const int* __restrict__ ei, int* cu, int* cm, int n) {
    int e = blockIdx.x * blockDim.x + threadIdx.x;
    if (e >= n) return;
    atomicAdd(&cu[ei[e]], 1);
    atomicAdd(&cm[ei[NE + e]], 1);
}

__global__ void __launch_bounds__(256)
scanA_kernel(const int* __restrict__ cnt, int* __restrict__ bsum, int n) {
    __shared__ int s[256];
    int b = blockIdx.x, t = threadIdx.x;
    int base = b * 2048 + t * 8;
    int sum = 0;
    if (base + 8 <= n) {
        int4 a = *(const int4*)&cnt[base];
        int4 c = *(const int4*)&cnt[base + 4];
        sum = a.x + a.y + a.z + a.w + c.x + c.y + c.z + c.w;
    } else {
        for (int j = 0; j < 8; j++) { int i = base + j; if (i < n) sum += cnt[i]; }
    }
    s[t] = sum;
    __syncthreads();
    for (int off = 128; off >= 1; off >>= 1) {
        if (t < off) s[t] += s[t + off];
        __syncthreads();
    }
    if (t == 0) bsum[b] = s[0];
}

__global__ void __launch_bounds__(256)
scanB_kernel(const int* __restrict__ bsum, int* __restrict__ boff, int nb,
             int* __restrict__ rp_total) {
    __shared__ int s[256];
    int t = threadIdx.x;
    int v = (t < nb) ? bsum[t] : 0;
    s[t] = v;
    __syncthreads();
    for (int off = 1; off < 256; off <<= 1) {
        int x = (t >= off) ? s[t - off] : 0;
        __syncthreads();
        s[t] += x;
        __syncthreads();
    }
    if (t < nb) boff[t] = s[t] - v;
    if (t == 255) rp_total[0] = s[255];
}

__global__ void __launch_bounds__(256)
scanC_kernel(const int* __restrict__ cnt, const int* __restrict__ boff,
             int* __restrict__ rp, int n) {
    __shared__ int s[256];
    int b = blockIdx.x, t = threadIdx.x;
    int base = b * 2048 + t * 8;
    int v[8];
    int sum = 0;
    if (base + 8 <= n) {
        int4 a = *(const int4*)&cnt[base];
        int4 c = *(const int4*)&cnt[base + 4];
        v[0] = a.x; v[1] = a.y; v[2] = a.z; v[3] = a.w;
        v[4] = c.x; v[5] = c.y; v[6] = c.z; v[7] = c.w;
#pragma unroll
        for (int j = 0; j < 8; j++) sum += v[j];
    } else {
#pragma unroll
        for (int j = 0; j < 8; j++) { int i = base + j; v[j] = (i < n) ? cnt[i] : 0; sum += v[j]; }
    }
    s[t] = sum;
    __syncthreads();
    for (int off = 1; off < 256; off <<= 1) {
        int x = (t >= off) ? s[t - off] : 0;
        __syncthreads();
        s[t] += x;
        __syncthreads();
    }
    int run = boff[b] + s[t] - sum;
    if (base + 8 <= n) {
        int o[8];
#pragma unroll
        for (int j = 0; j < 8; j++) { o[j] = run; run += v[j]; }
        *(int4*)&rp[base]     = make_int4(o[0], o[1], o[2], o[3]);
        *(int4*)&rp[base + 4] = make_int4(o[4], o[5], o[6], o[7]);
    } else {
#pragma unroll
        for (int j = 0; j < 8; j++) { int i = base + j; if (i < n) rp[i] = run; run += v[j]; }
    }
}

// user side records user id + edge id + reordered edge_attr per slot
__global__ void fill_kernel(const int* __restrict__ ei, const int* __restrict__ rpu,
                            const int* __restrict__ rpm, int* cu, int* cm,
                            int* __restrict__ eu, int* __restrict__ em,
                            int* __restrict__ us, int* __restrict__ ue,
                            const float* __restrict__ ea, float* __restrict__ eas, int n) {
    int e = blockIdx.x * blockDim.x + threadIdx.x;
    if (e >= n) return;
    int s = ei[e], d = ei[NE + e];
    int slot = rpu[s] + atomicAdd(&cu[s], 1);
    eu[slot] = d;
    us[slot] = s;
    ue[slot] = e;
    *(float2*)&eas[(size_t)slot * 2] = *(const float2*)&ea[(size_t)e * 2];
    em[rpm[d] + atomicAdd(&cm[d], 1)] = s;
}

// ---------------- weight converters (wave-coalesced B layout) ----------------
// c1wT2 chunk index: (((w*12+ks)*4+koff)*16 + l15), 8 bf16 per chunk.
__global__ void convert_w_kernel(const float* __restrict__ c1w, ushort_t* __restrict__ outT) {
    int i = blockIdx.x * 256 + threadIdx.x;
    if (i >= 384 * 128) return;
    int j = i & 7, chunk = i >> 3;
    int l15 = chunk & 15, koff = (chunk >> 4) & 3, wks = chunk >> 6;
    int ks = wks % 12, w = wks / 12;
    int col = w * 16 + l15, k = ks * 32 + koff * 8 + j;
    outT[i] = f2bf(c1w[k * H + col]);
}

// wT2 chunk index: (((w*8+ks)*4+koff)*16 + l15), 8 bf16 per chunk. k<128: wl, else wr.
__global__ void convert_conv_w_kernel(const float* __restrict__ wl, const float* __restrict__ wr,
                                      ushort_t* __restrict__ outT) {
    int i = blockIdx.x * 256 + threadIdx.x;
    if (i >= 128 * 256) return;
    int j = i & 7, chunk = i >> 3;
    int l15 = chunk & 15, koff = (chunk >> 4) & 3, wks = chunk >> 6;
    int ks = wks & 7, w = wks >> 3;
    int col = w * 16 + l15, k = ks * 32 + koff * 8 + j;
    float v = (k < 128) ? wl[k * H + col] : wr[(k - 128) * H + col];
    outT[i] = f2bf(v);
}

// ---------------- FUSED SAGE conv: gather+mean+MFMA, both directions ----------------
__global__ void __launch_bounds__(512)
conv_pair_kernel(const ushort_t* __restrict__ hu_in, const ushort_t* __restrict__ hm_in,
                 const int* __restrict__ rpu, const int* __restrict__ rpm,
                 const int* __restrict__ eu, const int* __restrict__ em,
                 const ushort_t* __restrict__ wTm, const float* __restrict__ blm,
                 ushort_t* __restrict__ outM,
                 const ushort_t* __restrict__ wTu, const float* __restrict__ blu,
                 ushort_t* __restrict__ outU, int ntM) {
    const ushort_t *nbr, *self, *wT; const float* bl; ushort_t* out;
    const int *rp, *nbl; int n, tile;
    if ((int)blockIdx.x < ntM) {
        tile = blockIdx.x; nbr = hu_in; self = hm_in; rp = rpm; nbl = em;
        wT = wTm; bl = blm; out = outM; n = NM;
    } else {
        tile = blockIdx.x - ntM; nbr = hm_in; self = hu_in; rp = rpu; nbl = eu;
        wT = wTu; bl = blu; out = outU; n = NU;
    }
    int node0 = tile * 64;
    int t = threadIdx.x, lane = t & 63, w = t >> 6;   // w in 0..7
    int l15 = lane & 15, koff = lane >> 4;
    __shared__ ushort_t AsAgg[64 * 128];   // 16 KB
    __shared__ ushort_t AsSelf[64 * 128];  // 16 KB
    char* Aa = (char*)AsAgg;
    char* Asf = (char*)AsSelf;

    // ---- phase 0: async self staging ----
#pragma unroll
    for (int it = 0; it < 2; it++) {
        int row = it * 32 + w * 4 + (lane >> 4);
        int node = node0 + row; if (node >= n) node = n - 1;
        int g = (lane & 15) ^ (row & 7);
        gload16(&self[(size_t)node * H + g * 8], Asf + it * 8192 + w * 1024);
    }

    // ---- phase 1: gather + mean, wave w -> rows w*8 .. w*8+7 ----
    for (int i = 0; i < 8; i++) {
        int row = w * 8 + i;
        int node = node0 + row;
        float a0 = 0.f, a1 = 0.f;
        int beg = 0, end = 0;
        if (node < n) { beg = rp[node]; end = rp[node + 1]; }
        int j = beg;
        for (; j + 4 <= end; j += 4) {
            int n0 = nbl[j], n1 = nbl[j + 1], n2 = nbl[j + 2], n3 = nbl[j + 3];
            uint_t v0 = *(const uint_t*)&nbr[(size_t)n0 * H + lane * 2];
            uint_t v1 = *(const uint_t*)&nbr[(size_t)n1 * H + lane * 2];
            uint_t v2 = *(const uint_t*)&nbr[(size_t)n2 * H + lane * 2];
            uint_t v3 = *(const uint_t*)&nbr[(size_t)n3 * H + lane * 2];
            a0 += (__uint_as_float((v0 & 0xffffu) << 16) + __uint_as_float((v1 & 0xffffu) << 16))
                + (__uint_as_float((v2 & 0xffffu) << 16) + __uint_as_float((v3 & 0xffffu) << 16));
            a1 += (__uint_as_float(v0 & 0xffff0000u) + __uint_as_float(v1 & 0xffff0000u))
                + (__uint_as_float(v2 & 0xffff0000u) + __uint_as_float(v3 & 0xffff0000u));
        }
        for (; j < end; j++) {
            uint_t v = *(const uint_t*)&nbr[(size_t)nbl[j] * H + lane * 2];
            a0 += __uint_as_float((v & 0xffffu) << 16);
            a1 += __uint_as_float(v & 0xffff0000u);
        }
        int deg = end - beg;
        float inv = 1.0f / (float)(deg > 1 ? deg : 1);
        uint_t r = (uint_t)f2bf(a0 * inv) | ((uint_t)f2bf(a1 * inv) << 16);
        *(uint_t*)(Aa + row * 256 + ((((lane >> 2)) ^ (row & 7)) << 4) + (lane & 3) * 4) = r;
    }

    // ---- B slice (coalesced layout) ----
    bf16x8 bw[8];
#pragma unroll
    for (int ks = 0; ks < 8; ks++)
        bw[ks] = *reinterpret_cast<const bf16x8*>(
            &wT[(size_t)((((w * 8 + ks) * 4 + koff) * 16 + l15)) * 8]);
    int col = w * 16 + l15;
    float bias0 = bl[col];
    int sw = l15 & 7;
    __syncthreads();   // drains gload vmcnt + LDS writes

    f32x4 acc[4];
#pragma unroll
    for (int rg = 0; rg < 4; rg++) acc[rg] = (f32x4){bias0, bias0, bias0, bias0};
#pragma unroll
    for (int ks = 0; ks < 8; ks++) {
#pragma unroll
        for (int rg = 0; rg < 4; rg++) {
            int row = rg * 16 + l15;
            const bf16x8 a = (ks < 4)
                ? *reinterpret_cast<const bf16x8*>(Aa  + row * 256 + (((ks * 4 + koff) ^ sw) << 4))
                : *reinterpret_cast<const bf16x8*>(Asf + row * 256 + ((((ks - 4) * 4 + koff) ^ sw) << 4));
            acc[rg] = __builtin_amdgcn_mfma_f32_16x16x32_bf16(a, bw[ks], acc[rg], 0, 0, 0);
        }
    }

#pragma unroll
    for (int rg = 0; rg < 4; rg++)
#pragma unroll
        for (int reg = 0; reg < 4; reg++) {
            int node = node0 + rg * 16 + koff * 4 + reg;
            if (node < n)
                out[(size_t)node * H + col] = f2bf(fmaxf(acc[rg][reg], 0.f));
        }
}

// ---------------- edge MLP via MFMA (user-order, hu-dedup, async staging) ----------------
__global__ void __launch_bounds__(512)
edge_mlp_mfma_kernel(const ushort_t* __restrict__ h_u, const ushort_t* __restrict__ h_m,
                     const float* __restrict__ eas, const float* __restrict__ ew,
                     const float* __restrict__ ebias,
                     const ushort_t* __restrict__ c1wT, const float* __restrict__ c1b,
                     const float* __restrict__ c2w, const float* __restrict__ c2b,
                     const int* __restrict__ us, const int* __restrict__ eu,
                     const int* __restrict__ ue, float* __restrict__ out) {
    const int ET = 64;
    // bijective XCD-chunked swizzle (m204)
    int nwg = gridDim.x;
    int q = nwg >> 3, r = nwg & 7;
    int xcd = blockIdx.x & 7, pos = blockIdx.x >> 3;
    int tile = (xcd < r ? xcd * (q + 1) : r * (q + 1) + (xcd - r) * q) + pos;
    int e0 = tile * ET;

    int t = threadIdx.x;
    int lane = t & 63, w = t >> 6;   // w in 0..7
    int l15 = lane & 15, koff = lane >> 4;

    __shared__ ushort_t Uh[ET * 128];   // 16 KB: unique hu rows (k 0..127)
    __shared__ ushort_t Mh[ET * 128];   // 16 KB: hm rows (k 128..255)
    __shared__ ushort_t As2[ET * 128];  // 16 KB: edge feats (k 256..383)
    __shared__ float part[8 * ET];      // 2 KB
    __shared__ int de[ET], ee[ET], uid_s[ET], ulist_s[ET];
    __shared__ int nuniq_s;
    char* Ub = (char*)Uh;
    char* Mb = (char*)Mh;
    char* Ab2 = (char*)As2;

    // ---- slot loads + in-wave dedup scan (wave 0 only; us sorted within tile) ----
    if (t < ET) {
        int sv = us[e0 + t];
        de[t] = eu[e0 + t];
        ee[t] = ue[e0 + t];
        int prev = __shfl_up(sv, 1, 64);
        int flag = (t > 0 && sv != prev) ? 1 : 0;
        int scan = flag;
#pragma unroll
        for (int off = 1; off < 64; off <<= 1) {
            int v = __shfl_up(scan, off, 64);
            if (t >= off) scan += v;
        }
        uid_s[t] = scan;
        if (flag || t == 0) ulist_s[scan] = sv;
        if (t == 63) nuniq_s = scan + 1;
    }
    __syncthreads();   // de/ee/uid/ulist/nuniq visible

    int nuniq = nuniq_s;

    // ---- async gather: unique hu rows (exec-masked) + all hm rows ----
    int rounds = (nuniq + 31) >> 5;
    for (int it = 0; it < rounds; it++) {
        int urow = it * 32 + w * 4 + (lane >> 4);
        if (urow < nuniq) {
            int g = (lane & 15) ^ (urow & 7);
            gload16(&h_u[(size_t)ulist_s[urow] * H + g * 8], Ub + it * 8192 + w * 1024);
        }
    }
#pragma unroll
    for (int it = 0; it < 2; it++) {
        int mrow = it * 32 + w * 4 + (lane >> 4);
        int g = (lane & 15) ^ (mrow & 7);
        gload16(&h_m[(size_t)de[mrow] * H + g * 8], Mb + it * 8192 + w * 1024);
    }

    // ---- B slice (coalesced layout; overlaps gather) ----
    bf16x8 bf_[12];
#pragma unroll
    for (int ks = 0; ks < 12; ks++)
        bf_[ks] = *reinterpret_cast<const bf16x8*>(
            &c1wT[(size_t)((((w * 12 + ks) * 4 + koff) * 16 + l15)) * 8]);

    // ---- edge-feature granules on VALU (streamed eas; overlaps gather) ----
#pragma unroll
    for (int it = 0; it < 2; it++) {
        int lin = it * 512 + t;          // 0..1023 = 64 rows x 16 granules
        int row = lin >> 4, g2 = lin & 15;
        int c = g2 * 8;
        float a0 = eas[(size_t)(e0 + row) * 2], a1 = eas[(size_t)(e0 + row) * 2 + 1];
        float4 w0a = *(const float4*)&ew[c];
        float4 w0b = *(const float4*)&ew[c + 4];
        float4 w1a = *(const float4*)&ew[H + c];
        float4 w1b = *(const float4*)&ew[H + c + 4];
        float4 bba = *(const float4*)&ebias[c];
        float4 bbb = *(const float4*)&ebias[c + 4];
        float v[8];
        v[0] = fmaxf(fmaf(a0, w0a.x, fmaf(a1, w1a.x, bba.x)), 0.f);
        v[1] = fmaxf(fmaf(a0, w0a.y, fmaf(a1, w1a.y, bba.y)), 0.f);
        v[2] = fmaxf(fmaf(a0, w0a.z, fmaf(a1, w1a.z, bba.z)), 0.f);
        v[3] = fmaxf(fmaf(a0, w0a.w, fmaf(a1, w1a.w, bba.w)), 0.f);
        v[4] = fmaxf(fmaf(a0, w0b.x, fmaf(a1, w1b.x, bbb.x)), 0.f);
        v[5] = fmaxf(fmaf(a0, w0b.y, fmaf(a1, w1b.y, bbb.y)), 0.f);
        v[6] = fmaxf(fmaf(a0, w0b.z, fmaf(a1, w1b.z, bbb.z)), 0.f);
        v[7] = fmaxf(fmaf(a0, w0b.w, fmaf(a1, w1b.w, bbb.w)), 0.f);
        union { ushort_t u[8]; uint4 qq; } pk;
#pragma unroll
        for (int j = 0; j < 8; j++) pk.u[j] = f2bf(v[j]);
        *(uint4*)(Ab2 + row * 256 + ((g2 ^ (row & 7)) << 4)) = pk.qq;
    }

    // preload per-slot unique-row indices for the MFMA A-read
    int uidr[4];
#pragma unroll
    for (int rg = 0; rg < 4; rg++) uidr[rg] = uid_s[rg * 16 + l15];

    __syncthreads();   // drains all gloads + LDS writes

    int sw = l15 & 7;
    int col = w * 16 + l15;
    float bias0 = c1b[col];
    f32x4 acc[4];
#pragma unroll
    for (int rg = 0; rg < 4; rg++) acc[rg] = (f32x4){bias0, bias0, bias0, bias0};
#pragma unroll
    for (int ks = 0; ks < 12; ks++) {
#pragma unroll
        for (int rg = 0; rg < 4; rg++) {
            int row = rg * 16 + l15;
            const bf16x8 a = (ks < 4)
                ? *reinterpret_cast<const bf16x8*>(
                      Ub + uidr[rg] * 256 + ((((ks * 4 + koff) ^ (uidr[rg] & 7))) << 4))
                : (ks < 8)
                ? *reinterpret_cast<const bf16x8*>(
                      Mb + row * 256 + ((((ks - 4) * 4 + koff) ^ sw) << 4))
                : *reinterpret_cast<const bf16x8*>(
                      Ab2 + row * 256 + ((((ks - 8) * 4 + koff) ^ sw) << 4));
            acc[rg] = __builtin_amdgcn_mfma_f32_16x16x32_bf16(a, bf_[ks], acc[rg], 0, 0, 0);
        }
    }

    float c2v = c2w[col];
#pragma unroll
    for (int rg = 0; rg < 4; rg++) {
#pragma unroll
        for (int reg = 0; reg < 4; reg++) {
            float p = fmaxf(acc[rg][reg], 0.f) * c2v;
#pragma unroll
            for (int off = 8; off >= 1; off >>= 1) p += __shfl_xor(p, off, 64);
            if (l15 == 0) part[w * ET + rg * 16 + koff * 4 + reg] = p;
        }
    }
    __syncthreads();
    if (t < ET) {
        float s = part[t];
#pragma unroll
        for (int ww = 1; ww < 8; ww++) s += part[ww * ET + t];
        out[ee[t]] = s + c2b[0];
    }
}

extern "C" void kernel_launch(void* const* d_in, const int* in_sizes, int n_in,
                              void* d_out, int out_size, void* d_ws, size_t ws_size,
                              hipStream_t stream) {
    const float* user_x     = (const float*)d_in[0];
    const float* merchant_x = (const float*)d_in[1];
    const float* edge_attr  = (const float*)d_in[2];
    const float* user_w     = (const float*)d_in[3];
    const float* user_b     = (const float*)d_in[4];
    const float* merch_w    = (const float*)d_in[5];
    const float* merch_b    = (const float*)d_in[6];
    const float* edge_w     = (const float*)d_in[7];
    const float* edge_b     = (const float*)d_in[8];
    const float* u2m_wl     = (const float*)d_in[9];
    const float* u2m_bl     = (const float*)d_in[10];
    const float* u2m_wr     = (const float*)d_in[11];
    const float* m2u_wl     = (const float*)d_in[12];
    const float* m2u_bl     = (const float*)d_in[13];
    const float* m2u_wr     = (const float*)d_in[14];
    const float* c1w        = (const float*)d_in[15];
    const float* c1b        = (const float*)d_in[16];
    const float* c2w        = (const float*)d_in[17];
    const float* c2b        = (const float*)d_in[18];
    const int*   ei         = (const int*)d_in[19];
    float* out = (float*)d_out;

    ushort_t* hu   = (ushort_t*)d_ws;
    ushort_t* hm   = hu  + (size_t)NU * H;
    ushort_t* hu2  = hm  + (size_t)NM * H;
    ushort_t* hm2  = hu2 + (size_t)NU * H;
    ushort_t* c1wT = hm2 + (size_t)NM * H;
    ushort_t* wTc  = c1wT + 384 * 128;
    int* rpu = (int*)(wTc + 4 * 128 * 256);
    int* rpm = rpu + (NU + 1);
    int* cu  = rpm + (NM + 1);
    int* cm  = cu + NU;
    int* eu  = cm + NM;
    int* em  = eu + NE;
    int* us  = em + NE;
    int* ue  = us + NE;
    float* eas = (float*)(ue + NE);        // 1.2M floats
    int* bsum_u = (int*)(eas + 2 * (size_t)NE);
    int* boff_u = bsum_u + 128;
    int* bsum_m = boff_u + 128;
    int* boff_m = bsum_m + 128;

    const int NBU = (NU + 2047) / 2048;
    const int NBM = (NM + 2047) / 2048;

    hipMemsetAsync(cu, 0, (size_t)(NU + NM) * sizeof(int), stream);

    encode_bf16_kernel<<<(NU * 16 + 255) / 256, 256, 0, stream>>>(user_x, user_w, user_b, hu, NU, 3);
    encode_bf16_kernel<<<(NM * 16 + 255) / 256, 256, 0, stream>>>(merchant_x, merch_w, merch_b, hm, NM, 2);
    convert_w_kernel<<<(384 * 128 + 255) / 256, 256, 0, stream>>>(c1w, c1wT);
    for (int l = 0; l < 2; l++) {
        convert_conv_w_kernel<<<128, 256, 0, stream>>>(
            u2m_wl + (size_t)l * H * H, u2m_wr + (size_t)l * H * H, wTc + (size_t)l * 128 * 256);
        convert_conv_w_kernel<<<128, 256, 0, stream>>>(
            m2u_wl + (size_t)l * H * H, m2u_wr + (size_t)l * H * H, wTc + (size_t)(2 + l) * 128 * 256);
    }

    count_kernel<<<(NE + 255) / 256, 256, 0, stream>>>(ei, cu, cm, NE);
    scanA_kernel<<<NBU, 256, 0, stream>>>(cu, bsum_u, NU);
    scanB_kernel<<<1, 256, 0, stream>>>(bsum_u, boff_u, NBU, rpu + NU);
    scanC_kernel<<<NBU, 256, 0, stream>>>(cu, boff_u, rpu, NU);
    scanA_kernel<<<NBM, 256, 0, stream>>>(cm, bsum_m, NM);
    scanB_kernel<<<1, 256, 0, stream>>>(bsum_m, boff_m, NBM, rpm + NM);
    scanC_kernel<<<NBM, 256, 0, stream>>>(cm, boff_m, rpm, NM);
    hipMemsetAsync(cu, 0, (size_t)(NU + NM) * sizeof(int), stream);
    fill_kernel<<<(NE + 255) / 256, 256, 0, stream>>>(ei, rpu, rpm, cu, cm, eu, em, us, ue,
                                                      edge_attr, eas, NE);

    const int CONV_TILES_M = (NM + 63) / 64;   // 782
    const int CONV_TILES_U = (NU + 63) / 64;   // 3125

    const ushort_t* pu = hu; const ushort_t* pm = hm;
    ushort_t* qu = hu2; ushort_t* qm = hm2;
    for (int l = 0; l < 2; l++) {
        conv_pair_kernel<<<CONV_TILES_M + CONV_TILES_U, 512, 0, stream>>>(
            pu, pm, rpu, rpm, eu, em,
            wTc + (size_t)l * 128 * 256, u2m_bl + (size_t)l * H, qm,
            wTc + (size_t)(2 + l) * 128 * 256, m2u_bl + (size_t)l * H, qu,
            CONV_TILES_M);
        const ushort_t* tu = pu; pu = qu; qu = (ushort_t*)tu;
        const ushort_t* tm = pm; pm = qm; qm = (ushort_t*)tm;
    }

    edge_mlp_mfma_kernel<<<NE / 64, 512, 0, stream>>>(pu, pm, eas, edge_w, edge_b,
                                                      c1wT, c1b, c2w, c2b, us, eu, ue, out);
}